// Round 4
// baseline (3370.702 us; speedup 1.0000x reference)
//
#include <hip/hip_runtime.h>

#define NN 50000
#define NE 600000

// ---------- edge-index dtype detection (int32 vs int64 storage) ----------
// If stored as int64 (little-endian, values < 2^31): every odd int32 slot is 0.
// If stored as int32: odd slots are dst indices, ~all nonzero.
__global__ __launch_bounds__(256) void detect_idx_kernel(const int* __restrict__ raw,
                                                          int* __restrict__ flag) {
    __shared__ int cnt;
    if (threadIdx.x == 0) cnt = 0;
    __syncthreads();
    int c = 0;
    for (int i = threadIdx.x; i < 2048; i += 256)
        if (raw[2 * i + 1] != 0) c++;
    atomicAdd(&cnt, c);
    __syncthreads();
    if (threadIdx.x == 0) *flag = (cnt > 10) ? 1 : 0;  // 1 => int32 layout
}

__global__ __launch_bounds__(256) void convert_idx_kernel(const void* __restrict__ raw,
                                                           const int* __restrict__ flag,
                                                           int* __restrict__ out, int n) {
    int i = blockIdx.x * 256 + threadIdx.x;
    if (i >= n) return;
    if (*flag) out[i] = ((const int*)raw)[i];
    else       out[i] = (int)((const long long*)raw)[i];
}

// ---------- float4 copy (init agg buffer with self features) ----------
__global__ __launch_bounds__(256) void copy4_kernel(const float4* __restrict__ src,
                                                     float4* __restrict__ dst, int n4) {
    int i = blockIdx.x * 256 + threadIdx.x;
    if (i < n4) dst[i] = src[i];
}

// ---------- scatter-add: accum[dst] += feat[src], D = D4*4 floats ----------
template <int D4>
__global__ __launch_bounds__(256) void scatter_add_kernel(const float* __restrict__ feat,
                                                           float* __restrict__ accum,
                                                           const int* __restrict__ srcIdx,
                                                           const int* __restrict__ dstIdx) {
    constexpr int SH = (D4 == 32) ? 5 : 6;
    long long gid = (long long)blockIdx.x * 256 + threadIdx.x;
    int e = (int)(gid >> SH);
    int c = (int)(gid & (D4 - 1));
    if (e >= NE) return;
    int s = srcIdx[e], d = dstIdx[e];
    const float4 v = *(const float4*)&feat[(size_t)s * (D4 * 4) + c * 4];
    float* p = &accum[(size_t)d * (D4 * 4) + c * 4];
    atomicAdd(p + 0, v.x);
    atomicAdd(p + 1, v.y);
    atomicAdd(p + 2, v.z);
    atomicAdd(p + 3, v.w);
}

// ---------- fp32 GEMM: C[M,N] = opt_relu(A[M,K] @ W[K,N] + bias[N]) ----------
// 64x64 tile, BK=16, 256 threads, 4x4 per thread, LDS-staged.
template <bool RELU>
__global__ __launch_bounds__(256) void gemm_kernel(const float* __restrict__ A,
                                                    const float* __restrict__ W,
                                                    const float* __restrict__ bias,
                                                    float* __restrict__ C,
                                                    int M, int K, int N) {
    __shared__ float As[16][64];
    __shared__ float Bs[16][64];
    const int tid = threadIdx.x;
    const int row0 = blockIdx.x * 64;
    const int col0 = blockIdx.y * 64;
    const int tx = tid & 15, ty = tid >> 4;
    const int arow = tid >> 2, ac4 = tid & 3;   // A tile load: 64 rows x 4 float4
    const int brow = tid >> 4, bc4 = tid & 15;  // B tile load: 16 rows x 16 float4
    float acc[4][4] = {};

    for (int k0 = 0; k0 < K; k0 += 16) {
        float4 av = make_float4(0.f, 0.f, 0.f, 0.f);
        const int gm = row0 + arow;
        if (gm < M) av = *(const float4*)&A[(size_t)gm * K + k0 + ac4 * 4];
        As[ac4 * 4 + 0][arow] = av.x;
        As[ac4 * 4 + 1][arow] = av.y;
        As[ac4 * 4 + 2][arow] = av.z;
        As[ac4 * 4 + 3][arow] = av.w;
        *(float4*)&Bs[brow][bc4 * 4] =
            *(const float4*)&W[(size_t)(k0 + brow) * N + col0 + bc4 * 4];
        __syncthreads();
#pragma unroll
        for (int kk = 0; kk < 16; ++kk) {
            const float4 a = *(const float4*)&As[kk][ty * 4];
            const float4 b = *(const float4*)&Bs[kk][tx * 4];
            acc[0][0] += a.x * b.x; acc[0][1] += a.x * b.y; acc[0][2] += a.x * b.z; acc[0][3] += a.x * b.w;
            acc[1][0] += a.y * b.x; acc[1][1] += a.y * b.y; acc[1][2] += a.y * b.z; acc[1][3] += a.y * b.w;
            acc[2][0] += a.z * b.x; acc[2][1] += a.z * b.y; acc[2][2] += a.z * b.z; acc[2][3] += a.z * b.w;
            acc[3][0] += a.w * b.x; acc[3][1] += a.w * b.y; acc[3][2] += a.w * b.z; acc[3][3] += a.w * b.w;
        }
        __syncthreads();
    }

#pragma unroll
    for (int i = 0; i < 4; ++i) {
        const int gm = row0 + ty * 4 + i;
        if (gm >= M) continue;
        float4 o;
        o.x = acc[i][0] + bias[col0 + tx * 4 + 0];
        o.y = acc[i][1] + bias[col0 + tx * 4 + 1];
        o.z = acc[i][2] + bias[col0 + tx * 4 + 2];
        o.w = acc[i][3] + bias[col0 + tx * 4 + 3];
        if (RELU) {
            o.x = fmaxf(o.x, 0.f); o.y = fmaxf(o.y, 0.f);
            o.z = fmaxf(o.z, 0.f); o.w = fmaxf(o.w, 0.f);
        }
        *(float4*)&C[(size_t)gm * N + col0 + tx * 4] = o;
    }
}

// ---------- final: o = A[M,256] @ W[256,16] + b; out = log_softmax(o) ----------
// 256 threads = 16 rows x 16 cols per block; 16-lane shuffle reductions.
__global__ __launch_bounds__(256) void head_kernel(const float* __restrict__ A,
                                                    const float* __restrict__ W,
                                                    const float* __restrict__ bias,
                                                    float* __restrict__ out, int M) {
    __shared__ float Ws[4096];  // [256][16]
    for (int i = threadIdx.x; i < 1024; i += 256)
        *(float4*)&Ws[i * 4] = *(const float4*)&W[i * 4];
    __syncthreads();

    const int r = threadIdx.x >> 4, c = threadIdx.x & 15;
    const int gm = blockIdx.x * 16 + r;
    float acc = 0.f;
    if (gm < M) {
        const float* a = &A[(size_t)gm * 256];
#pragma unroll 8
        for (int k = 0; k < 256; k += 4) {
            const float4 v = *(const float4*)&a[k];
            acc += v.x * Ws[(k + 0) * 16 + c];
            acc += v.y * Ws[(k + 1) * 16 + c];
            acc += v.z * Ws[(k + 2) * 16 + c];
            acc += v.w * Ws[(k + 3) * 16 + c];
        }
        acc += bias[c];
    }
    float m = acc;
#pragma unroll
    for (int o = 8; o; o >>= 1) m = fmaxf(m, __shfl_xor(m, o, 16));
    const float e = expf(acc - m);
    float s = e;
#pragma unroll
    for (int o = 8; o; o >>= 1) s += __shfl_xor(s, o, 16);
    if (gm < M) out[(size_t)gm * 16 + c] = (acc - m) - logf(s);
}

extern "C" void kernel_launch(void* const* d_in, const int* in_sizes, int n_in,
                              void* d_out, int out_size, void* d_ws, size_t ws_size,
                              hipStream_t stream) {
    (void)in_sizes; (void)n_in; (void)out_size; (void)ws_size;
    const float* x   = (const float*)d_in[0];
    const void*  ei  = d_in[1];
    const float* w1a = (const float*)d_in[2];
    const float* b1a = (const float*)d_in[3];
    const float* w2a = (const float*)d_in[4];
    const float* b2a = (const float*)d_in[5];
    const float* w1b = (const float*)d_in[6];
    const float* b1b = (const float*)d_in[7];
    const float* w2b = (const float*)d_in[8];
    const float* b2b = (const float*)d_in[9];
    float* out = (float*)d_out;

    // ws layout (floats): B0 | B1 | B2 (each 50000*256) | idx (1.2M int32) | flag
    const size_t BUF = (size_t)NN * 256;
    float* B0 = (float*)d_ws;           // z1 (first 128 cols) then z2
    float* B1 = B0 + BUF;               // m1 then m2
    float* B2 = B1 + BUF;               // h1
    int* idx  = (int*)(B2 + BUF);
    int* flag = idx + 2 * NE;

    detect_idx_kernel<<<1, 256, 0, stream>>>((const int*)ei, flag);
    convert_idx_kernel<<<(2 * NE + 255) / 256, 256, 0, stream>>>(ei, flag, idx, 2 * NE);
    const int* srcI = idx;
    const int* dstI = idx + NE;

    // ---- conv1: z1 = x + segment_sum(x[src], dst), D=128 ----
    copy4_kernel<<<(NN * 128 / 4 + 255) / 256, 256, 0, stream>>>(
        (const float4*)x, (float4*)B0, NN * 128 / 4);
    scatter_add_kernel<32><<<(NE * 32 + 255) / 256, 256, 0, stream>>>(x, B0, srcI, dstI);
    // m1 = relu(z1 @ w1a + b1a)
    gemm_kernel<true><<<dim3((NN + 63) / 64, 4), 256, 0, stream>>>(B0, w1a, b1a, B1, NN, 128, 256);
    // h1 = relu(m1 @ w2a + b2a)   (conv1 output + outer relu)
    gemm_kernel<true><<<dim3((NN + 63) / 64, 4), 256, 0, stream>>>(B1, w2a, b2a, B2, NN, 256, 256);

    // ---- conv2: z2 = h1 + segment_sum(h1[src], dst), D=256 ----
    copy4_kernel<<<(NN * 256 / 4 + 255) / 256, 256, 0, stream>>>(
        (const float4*)B2, (float4*)B0, NN * 256 / 4);
    scatter_add_kernel<64><<<(NE * 64 + 255) / 256, 256, 0, stream>>>(B2, B0, srcI, dstI);
    // m2 = relu(z2 @ w1b + b1b)
    gemm_kernel<true><<<dim3((NN + 63) / 64, 4), 256, 0, stream>>>(B0, w1b, b1b, B1, NN, 256, 256);
    // out = log_softmax(m2 @ w2b + b2b)
    head_kernel<<<(NN + 15) / 16, 256, 0, stream>>>(B1, w2b, b2b, out, NN);
}

// Round 5
// 645.594 us; speedup vs baseline: 5.2211x; 5.2211x over previous
//
#include <hip/hip_runtime.h>

#define NN 50000
#define NE 600000

// ---------- edge-index dtype detection (int32 vs int64 storage) ----------
__global__ __launch_bounds__(256) void detect_idx_kernel(const int* __restrict__ raw,
                                                          int* __restrict__ flag) {
    __shared__ int cnt;
    if (threadIdx.x == 0) cnt = 0;
    __syncthreads();
    int c = 0;
    for (int i = threadIdx.x; i < 2048; i += 256)
        if (raw[2 * i + 1] != 0) c++;
    atomicAdd(&cnt, c);
    __syncthreads();
    if (threadIdx.x == 0) *flag = (cnt > 10) ? 1 : 0;  // 1 => int32 layout
}

__global__ __launch_bounds__(256) void convert_idx_kernel(const void* __restrict__ raw,
                                                           const int* __restrict__ flag,
                                                           int* __restrict__ out, int n) {
    int i = blockIdx.x * 256 + threadIdx.x;
    if (i >= n) return;
    if (*flag) out[i] = ((const int*)raw)[i];
    else       out[i] = (int)((const long long*)raw)[i];
}

// ---------- CSR build: deg count -> scan -> fill ----------
__global__ __launch_bounds__(256) void count_deg_kernel(const int* __restrict__ dstIdx,
                                                         int* __restrict__ deg) {
    int e = blockIdx.x * 256 + threadIdx.x;
    if (e < NE) atomicAdd(&deg[dstIdx[e]], 1);
}

// single-block exclusive scan over NN degrees -> rowptr[NN+1]; also init cursor
__global__ __launch_bounds__(1024) void scan_kernel(const int* __restrict__ deg,
                                                     int* __restrict__ rowptr,
                                                     int* __restrict__ cursor) {
    __shared__ int part[1024];
    const int t = threadIdx.x;
    const int CH = (NN + 1023) / 1024;  // 49
    const int start = t * CH;
    const int end = min(start + CH, NN);
    int sum = 0;
    for (int i = start; i < end; i++) sum += deg[i];
    part[t] = sum;
    __syncthreads();
    for (int off = 1; off < 1024; off <<= 1) {
        int v = (t >= off) ? part[t - off] : 0;
        __syncthreads();
        part[t] += v;
        __syncthreads();
    }
    int prefix = (t == 0) ? 0 : part[t - 1];
    for (int i = start; i < end; i++) {
        rowptr[i] = prefix;
        cursor[i] = prefix;
        prefix += deg[i];
    }
    if (t == 1023) rowptr[NN] = part[1023];
}

__global__ __launch_bounds__(256) void fill_csr_kernel(const int* __restrict__ srcIdx,
                                                        const int* __restrict__ dstIdx,
                                                        int* __restrict__ cursor,
                                                        int* __restrict__ csr_src) {
    int e = blockIdx.x * 256 + threadIdx.x;
    if (e >= NE) return;
    int pos = atomicAdd(&cursor[dstIdx[e]], 1);
    csr_src[pos] = srcIdx[e];
}

// ---------- gather-aggregate: z[n] = feat[n] + sum_{s in adj(n)} feat[s] ----------
// One wave per node; lane l owns D/64 contiguous floats. Coalesced 512B/1KB row reads.
template <int D>
__global__ __launch_bounds__(256) void aggregate_kernel(const float* __restrict__ feat,
                                                         float* __restrict__ z,
                                                         const int* __restrict__ rowptr,
                                                         const int* __restrict__ csr_src) {
    const int wave = blockIdx.x * 4 + (threadIdx.x >> 6);
    const int lane = threadIdx.x & 63;
    if (wave >= NN) return;
    const int rbeg = rowptr[wave];
    const int rend = rowptr[wave + 1];

    if (D == 256) {
        float4 acc = *(const float4*)&feat[(size_t)wave * 256 + lane * 4];
        int j = rbeg;
        for (; j + 1 < rend; j += 2) {
            const int s0 = csr_src[j], s1 = csr_src[j + 1];
            const float4 v0 = *(const float4*)&feat[(size_t)s0 * 256 + lane * 4];
            const float4 v1 = *(const float4*)&feat[(size_t)s1 * 256 + lane * 4];
            acc.x += v0.x + v1.x; acc.y += v0.y + v1.y;
            acc.z += v0.z + v1.z; acc.w += v0.w + v1.w;
        }
        if (j < rend) {
            const int s = csr_src[j];
            const float4 v = *(const float4*)&feat[(size_t)s * 256 + lane * 4];
            acc.x += v.x; acc.y += v.y; acc.z += v.z; acc.w += v.w;
        }
        *(float4*)&z[(size_t)wave * 256 + lane * 4] = acc;
    } else {  // D == 128
        float2 acc = *(const float2*)&feat[(size_t)wave * 128 + lane * 2];
        int j = rbeg;
        for (; j + 1 < rend; j += 2) {
            const int s0 = csr_src[j], s1 = csr_src[j + 1];
            const float2 v0 = *(const float2*)&feat[(size_t)s0 * 128 + lane * 2];
            const float2 v1 = *(const float2*)&feat[(size_t)s1 * 128 + lane * 2];
            acc.x += v0.x + v1.x; acc.y += v0.y + v1.y;
        }
        if (j < rend) {
            const int s = csr_src[j];
            const float2 v = *(const float2*)&feat[(size_t)s * 128 + lane * 2];
            acc.x += v.x; acc.y += v.y;
        }
        *(float2*)&z[(size_t)wave * 128 + lane * 2] = acc;
    }
}

// ---------- fp32 GEMM: C[M,N] = opt_relu(A[M,K] @ W[K,N] + bias[N]) ----------
template <bool RELU>
__global__ __launch_bounds__(256) void gemm_kernel(const float* __restrict__ A,
                                                    const float* __restrict__ W,
                                                    const float* __restrict__ bias,
                                                    float* __restrict__ C,
                                                    int M, int K, int N) {
    __shared__ float As[16][64];
    __shared__ float Bs[16][64];
    const int tid = threadIdx.x;
    const int row0 = blockIdx.x * 64;
    const int col0 = blockIdx.y * 64;
    const int tx = tid & 15, ty = tid >> 4;
    const int arow = tid >> 2, ac4 = tid & 3;
    const int brow = tid >> 4, bc4 = tid & 15;
    float acc[4][4] = {};

    for (int k0 = 0; k0 < K; k0 += 16) {
        float4 av = make_float4(0.f, 0.f, 0.f, 0.f);
        const int gm = row0 + arow;
        if (gm < M) av = *(const float4*)&A[(size_t)gm * K + k0 + ac4 * 4];
        As[ac4 * 4 + 0][arow] = av.x;
        As[ac4 * 4 + 1][arow] = av.y;
        As[ac4 * 4 + 2][arow] = av.z;
        As[ac4 * 4 + 3][arow] = av.w;
        *(float4*)&Bs[brow][bc4 * 4] =
            *(const float4*)&W[(size_t)(k0 + brow) * N + col0 + bc4 * 4];
        __syncthreads();
#pragma unroll
        for (int kk = 0; kk < 16; ++kk) {
            const float4 a = *(const float4*)&As[kk][ty * 4];
            const float4 b = *(const float4*)&Bs[kk][tx * 4];
            acc[0][0] += a.x * b.x; acc[0][1] += a.x * b.y; acc[0][2] += a.x * b.z; acc[0][3] += a.x * b.w;
            acc[1][0] += a.y * b.x; acc[1][1] += a.y * b.y; acc[1][2] += a.y * b.z; acc[1][3] += a.y * b.w;
            acc[2][0] += a.z * b.x; acc[2][1] += a.z * b.y; acc[2][2] += a.z * b.z; acc[2][3] += a.z * b.w;
            acc[3][0] += a.w * b.x; acc[3][1] += a.w * b.y; acc[3][2] += a.w * b.z; acc[3][3] += a.w * b.w;
        }
        __syncthreads();
    }

#pragma unroll
    for (int i = 0; i < 4; ++i) {
        const int gm = row0 + ty * 4 + i;
        if (gm >= M) continue;
        float4 o;
        o.x = acc[i][0] + bias[col0 + tx * 4 + 0];
        o.y = acc[i][1] + bias[col0 + tx * 4 + 1];
        o.z = acc[i][2] + bias[col0 + tx * 4 + 2];
        o.w = acc[i][3] + bias[col0 + tx * 4 + 3];
        if (RELU) {
            o.x = fmaxf(o.x, 0.f); o.y = fmaxf(o.y, 0.f);
            o.z = fmaxf(o.z, 0.f); o.w = fmaxf(o.w, 0.f);
        }
        *(float4*)&C[(size_t)gm * N + col0 + tx * 4] = o;
    }
}

// ---------- final: o = A[M,256] @ W[256,16] + b; out = log_softmax(o) ----------
__global__ __launch_bounds__(256) void head_kernel(const float* __restrict__ A,
                                                    const float* __restrict__ W,
                                                    const float* __restrict__ bias,
                                                    float* __restrict__ out, int M) {
    __shared__ float Ws[4096];  // [256][16]
    for (int i = threadIdx.x; i < 1024; i += 256)
        *(float4*)&Ws[i * 4] = *(const float4*)&W[i * 4];
    __syncthreads();

    const int r = threadIdx.x >> 4, c = threadIdx.x & 15;
    const int gm = blockIdx.x * 16 + r;
    float acc = 0.f;
    if (gm < M) {
        const float* a = &A[(size_t)gm * 256];
#pragma unroll 8
        for (int k = 0; k < 256; k += 4) {
            const float4 v = *(const float4*)&a[k];
            acc += v.x * Ws[(k + 0) * 16 + c];
            acc += v.y * Ws[(k + 1) * 16 + c];
            acc += v.z * Ws[(k + 2) * 16 + c];
            acc += v.w * Ws[(k + 3) * 16 + c];
        }
        acc += bias[c];
    }
    float m = acc;
#pragma unroll
    for (int o = 8; o; o >>= 1) m = fmaxf(m, __shfl_xor(m, o, 16));
    const float e = expf(acc - m);
    float s = e;
#pragma unroll
    for (int o = 8; o; o >>= 1) s += __shfl_xor(s, o, 16);
    if (gm < M) out[(size_t)gm * 16 + c] = (acc - m) - logf(s);
}

extern "C" void kernel_launch(void* const* d_in, const int* in_sizes, int n_in,
                              void* d_out, int out_size, void* d_ws, size_t ws_size,
                              hipStream_t stream) {
    (void)in_sizes; (void)n_in; (void)out_size; (void)ws_size;
    const float* x   = (const float*)d_in[0];
    const void*  ei  = d_in[1];
    const float* w1a = (const float*)d_in[2];
    const float* b1a = (const float*)d_in[3];
    const float* w2a = (const float*)d_in[4];
    const float* b2a = (const float*)d_in[5];
    const float* w1b = (const float*)d_in[6];
    const float* b1b = (const float*)d_in[7];
    const float* w2b = (const float*)d_in[8];
    const float* b2b = (const float*)d_in[9];
    float* out = (float*)d_out;

    // ws layout: B0 | B1 | B2 (each 50000*256 f32) | ints
    const size_t BUF = (size_t)NN * 256;
    float* B0 = (float*)d_ws;   // z1 / z2
    float* B1 = B0 + BUF;       // m1 / m2
    float* B2 = B1 + BUF;       // h1
    int* idx     = (int*)(B2 + BUF);     // 2*NE
    int* flag    = idx + 2 * NE;         // 1
    int* deg     = flag + 1;             // NN
    int* rowptr  = deg + NN;             // NN+1
    int* cursor  = rowptr + NN + 1;      // NN
    int* csr_src = cursor + NN;          // NE

    // ---- edge index normalize ----
    detect_idx_kernel<<<1, 256, 0, stream>>>((const int*)ei, flag);
    convert_idx_kernel<<<(2 * NE + 255) / 256, 256, 0, stream>>>(ei, flag, idx, 2 * NE);
    const int* srcI = idx;
    const int* dstI = idx + NE;

    // ---- CSR build (by dst) ----
    hipMemsetAsync(deg, 0, NN * sizeof(int), stream);
    count_deg_kernel<<<(NE + 255) / 256, 256, 0, stream>>>(dstI, deg);
    scan_kernel<<<1, 1024, 0, stream>>>(deg, rowptr, cursor);
    fill_csr_kernel<<<(NE + 255) / 256, 256, 0, stream>>>(srcI, dstI, cursor, csr_src);

    const int aggBlocks = (NN + 3) / 4;  // 4 waves/block, 1 wave/node

    // ---- conv1 ----
    aggregate_kernel<128><<<aggBlocks, 256, 0, stream>>>(x, B0, rowptr, csr_src);
    gemm_kernel<true><<<dim3((NN + 63) / 64, 4), 256, 0, stream>>>(B0, w1a, b1a, B1, NN, 128, 256);
    gemm_kernel<true><<<dim3((NN + 63) / 64, 4), 256, 0, stream>>>(B1, w2a, b2a, B2, NN, 256, 256);

    // ---- conv2 ----
    aggregate_kernel<256><<<aggBlocks, 256, 0, stream>>>(B2, B0, rowptr, csr_src);
    gemm_kernel<true><<<dim3((NN + 63) / 64, 4), 256, 0, stream>>>(B0, w1b, b1b, B1, NN, 256, 256);
    head_kernel<<<(NN + 15) / 16, 256, 0, stream>>>(B1, w2b, b2b, out, NN);
}

// Round 6
// 393.755 us; speedup vs baseline: 8.5604x; 1.6396x over previous
//
#include <hip/hip_runtime.h>

#define NN 50000
#define NE 600000

typedef short v8s __attribute__((ext_vector_type(8)));
typedef float v4f __attribute__((ext_vector_type(4)));

#define LDSW 40  // shorts per LDS tile row: 32 data + 8 pad (80B, 16B-aligned)

__device__ __forceinline__ float b2f(ushort u) {
    union { unsigned u; float f; } v; v.u = ((unsigned)u) << 16; return v.f;
}
__device__ __forceinline__ ushort f2b(float f) {
    union { float f; unsigned u; } v; v.f = f;
    unsigned r = v.u + 0x7FFFu + ((v.u >> 16) & 1u);  // RNE
    return (ushort)(r >> 16);
}

// ---------- edge-index dtype detection (int32 vs int64 storage) ----------
__global__ __launch_bounds__(256) void detect_idx_kernel(const int* __restrict__ raw,
                                                          int* __restrict__ flag) {
    __shared__ int cnt;
    if (threadIdx.x == 0) cnt = 0;
    __syncthreads();
    int c = 0;
    for (int i = threadIdx.x; i < 2048; i += 256)
        if (raw[2 * i + 1] != 0) c++;
    atomicAdd(&cnt, c);
    __syncthreads();
    if (threadIdx.x == 0) *flag = (cnt > 10) ? 1 : 0;  // 1 => int32 layout
}

__global__ __launch_bounds__(256) void convert_idx_kernel(const void* __restrict__ raw,
                                                           const int* __restrict__ flag,
                                                           int* __restrict__ out, int n) {
    int i = blockIdx.x * 256 + threadIdx.x;
    if (i >= n) return;
    if (*flag) out[i] = ((const int*)raw)[i];
    else       out[i] = (int)((const long long*)raw)[i];
}

// ---------- CSR build ----------
__global__ __launch_bounds__(256) void count_deg_kernel(const int* __restrict__ dstIdx,
                                                         int* __restrict__ deg) {
    int e = blockIdx.x * 256 + threadIdx.x;
    if (e < NE) atomicAdd(&deg[dstIdx[e]], 1);
}

__global__ __launch_bounds__(1024) void scan_kernel(const int* __restrict__ deg,
                                                     int* __restrict__ rowptr,
                                                     int* __restrict__ cursor) {
    __shared__ int part[1024];
    const int t = threadIdx.x;
    const int CH = (NN + 1023) / 1024;
    const int start = t * CH;
    const int end = min(start + CH, NN);
    int sum = 0;
    for (int i = start; i < end; i++) sum += deg[i];
    part[t] = sum;
    __syncthreads();
    for (int off = 1; off < 1024; off <<= 1) {
        int v = (t >= off) ? part[t - off] : 0;
        __syncthreads();
        part[t] += v;
        __syncthreads();
    }
    int prefix = (t == 0) ? 0 : part[t - 1];
    for (int i = start; i < end; i++) {
        rowptr[i] = prefix;
        cursor[i] = prefix;
        prefix += deg[i];
    }
    if (t == 1023) rowptr[NN] = part[1023];
}

__global__ __launch_bounds__(256) void fill_csr_kernel(const int* __restrict__ srcIdx,
                                                        const int* __restrict__ dstIdx,
                                                        int* __restrict__ cursor,
                                                        int* __restrict__ csr_src) {
    int e = blockIdx.x * 256 + threadIdx.x;
    if (e >= NE) return;
    int pos = atomicAdd(&cursor[dstIdx[e]], 1);
    csr_src[pos] = srcIdx[e];
}

// ---------- fp32 -> bf16 converters ----------
__global__ __launch_bounds__(256) void cvt_f32_bf16_kernel(const float* __restrict__ in,
                                                            ushort* __restrict__ out, int n4) {
    int i = blockIdx.x * 256 + threadIdx.x;
    if (i >= n4) return;
    const float4 v = *(const float4*)&in[(size_t)i * 4];
    ushort4 o;
    o.x = f2b(v.x); o.y = f2b(v.y); o.z = f2b(v.z); o.w = f2b(v.w);
    *(ushort4*)&out[(size_t)i * 4] = o;
}

// out[n*K+k] = bf16(in[k*N+n])  (weights: tiny, once per call)
__global__ __launch_bounds__(256) void transpose_cvt_kernel(const float* __restrict__ in,
                                                             ushort* __restrict__ out,
                                                             int K, int N) {
    int idx = blockIdx.x * 256 + threadIdx.x;
    if (idx >= K * N) return;
    int n = idx / K, k = idx - n * K;
    out[idx] = f2b(in[(size_t)k * N + n]);
}

// ---------- gather-aggregate (bf16 in/out, fp32 accum) ----------
template <int D>
__global__ __launch_bounds__(256) void aggregate_bf16_kernel(const ushort* __restrict__ feat,
                                                              ushort* __restrict__ z,
                                                              const int* __restrict__ rowptr,
                                                              const int* __restrict__ csr_src) {
    const int node = blockIdx.x * 4 + (threadIdx.x >> 6);
    const int lane = threadIdx.x & 63;
    if (node >= NN) return;
    const int rbeg = rowptr[node];
    const int rend = rowptr[node + 1];

    if (D == 256) {
        const size_t base = (size_t)node * 256 + lane * 4;
        uint2 sv = *(const uint2*)&feat[base];
        float a0 = b2f((ushort)sv.x), a1 = b2f((ushort)(sv.x >> 16));
        float a2 = b2f((ushort)sv.y), a3 = b2f((ushort)(sv.y >> 16));
        int j = rbeg;
        for (; j + 3 < rend; j += 4) {
            const int s0 = csr_src[j], s1 = csr_src[j + 1];
            const int s2 = csr_src[j + 2], s3 = csr_src[j + 3];
            const uint2 v0 = *(const uint2*)&feat[(size_t)s0 * 256 + lane * 4];
            const uint2 v1 = *(const uint2*)&feat[(size_t)s1 * 256 + lane * 4];
            const uint2 v2 = *(const uint2*)&feat[(size_t)s2 * 256 + lane * 4];
            const uint2 v3 = *(const uint2*)&feat[(size_t)s3 * 256 + lane * 4];
            a0 += b2f((ushort)v0.x) + b2f((ushort)v1.x) + b2f((ushort)v2.x) + b2f((ushort)v3.x);
            a1 += b2f((ushort)(v0.x >> 16)) + b2f((ushort)(v1.x >> 16)) + b2f((ushort)(v2.x >> 16)) + b2f((ushort)(v3.x >> 16));
            a2 += b2f((ushort)v0.y) + b2f((ushort)v1.y) + b2f((ushort)v2.y) + b2f((ushort)v3.y);
            a3 += b2f((ushort)(v0.y >> 16)) + b2f((ushort)(v1.y >> 16)) + b2f((ushort)(v2.y >> 16)) + b2f((ushort)(v3.y >> 16));
        }
        for (; j < rend; j++) {
            const uint2 v = *(const uint2*)&feat[(size_t)csr_src[j] * 256 + lane * 4];
            a0 += b2f((ushort)v.x); a1 += b2f((ushort)(v.x >> 16));
            a2 += b2f((ushort)v.y); a3 += b2f((ushort)(v.y >> 16));
        }
        uint2 o;
        o.x = (uint)f2b(a0) | ((uint)f2b(a1) << 16);
        o.y = (uint)f2b(a2) | ((uint)f2b(a3) << 16);
        *(uint2*)&z[base] = o;
    } else {  // D == 128
        const size_t base = (size_t)node * 128 + lane * 2;
        uint sv = *(const uint*)&feat[base];
        float a0 = b2f((ushort)sv), a1 = b2f((ushort)(sv >> 16));
        int j = rbeg;
        for (; j + 3 < rend; j += 4) {
            const int s0 = csr_src[j], s1 = csr_src[j + 1];
            const int s2 = csr_src[j + 2], s3 = csr_src[j + 3];
            const uint v0 = *(const uint*)&feat[(size_t)s0 * 128 + lane * 2];
            const uint v1 = *(const uint*)&feat[(size_t)s1 * 128 + lane * 2];
            const uint v2 = *(const uint*)&feat[(size_t)s2 * 128 + lane * 2];
            const uint v3 = *(const uint*)&feat[(size_t)s3 * 128 + lane * 2];
            a0 += b2f((ushort)v0) + b2f((ushort)v1) + b2f((ushort)v2) + b2f((ushort)v3);
            a1 += b2f((ushort)(v0 >> 16)) + b2f((ushort)(v1 >> 16)) + b2f((ushort)(v2 >> 16)) + b2f((ushort)(v3 >> 16));
        }
        for (; j < rend; j++) {
            const uint v = *(const uint*)&feat[(size_t)csr_src[j] * 128 + lane * 2];
            a0 += b2f((ushort)v); a1 += b2f((ushort)(v >> 16));
        }
        *(uint*)&z[base] = (uint)f2b(a0) | ((uint)f2b(a1) << 16);
    }
}

// ---------- bf16 MFMA GEMM: C[M,256] = relu(A[M,K] @ W + bias), W given as Wt[256][K] ----------
// 128x128 tile, BK=32, 4 waves (2x2), each wave 64x64 = 4x4 fragments of 16x16x32.
// Fragment layouts (m89/m91-verified): A row=l&15 k=(l>>4)*8+j; B col=l&15 same k;
// D col=l&15, row=(l>>4)*4+reg.
template <int K>
__global__ __launch_bounds__(256) void gemm_bf16_kernel(const ushort* __restrict__ A,
                                                         const ushort* __restrict__ Bt,
                                                         const float* __restrict__ bias,
                                                         ushort* __restrict__ C,
                                                         int M) {
    __shared__ ushort lA[128 * LDSW];
    __shared__ ushort lB[128 * LDSW];
    const int tid = threadIdx.x;
    const int lane = tid & 63;
    const int wv = tid >> 6;
    const int wm = wv >> 1, wn = wv & 1;
    const int row0 = blockIdx.x * 128;
    const int col0 = blockIdx.y * 128;
    const int l15 = lane & 15;
    const int kq = lane >> 4;   // 0..3
    // staging: thread t -> tile row t>>1, 16-elem half (t&1)
    const int sr = tid >> 1;
    const int sc = (tid & 1) * 16;

    v4f acc[4][4];
#pragma unroll
    for (int m = 0; m < 4; m++)
#pragma unroll
        for (int n = 0; n < 4; n++) acc[m][n] = (v4f){0.f, 0.f, 0.f, 0.f};

    for (int k0 = 0; k0 < K; k0 += 32) {
        const int gr = row0 + sr;
        v8s a0 = {}, a1 = {};
        if (gr < M) {
            a0 = *(const v8s*)&A[(size_t)gr * K + k0 + sc];
            a1 = *(const v8s*)&A[(size_t)gr * K + k0 + sc + 8];
        }
        const v8s b0 = *(const v8s*)&Bt[(size_t)(col0 + sr) * K + k0 + sc];
        const v8s b1 = *(const v8s*)&Bt[(size_t)(col0 + sr) * K + k0 + sc + 8];
        *(v8s*)&lA[sr * LDSW + sc]     = a0;
        *(v8s*)&lA[sr * LDSW + sc + 8] = a1;
        *(v8s*)&lB[sr * LDSW + sc]     = b0;
        *(v8s*)&lB[sr * LDSW + sc + 8] = b1;
        __syncthreads();

        v8s af[4], bf[4];
#pragma unroll
        for (int m = 0; m < 4; m++)
            af[m] = *(const v8s*)&lA[(wm * 64 + m * 16 + l15) * LDSW + kq * 8];
#pragma unroll
        for (int n = 0; n < 4; n++)
            bf[n] = *(const v8s*)&lB[(wn * 64 + n * 16 + l15) * LDSW + kq * 8];
#pragma unroll
        for (int m = 0; m < 4; m++)
#pragma unroll
            for (int n = 0; n < 4; n++)
                acc[m][n] = __builtin_amdgcn_mfma_f32_16x16x32_bf16(af[m], bf[n], acc[m][n], 0, 0, 0);
        __syncthreads();
    }

#pragma unroll
    for (int n = 0; n < 4; n++) {
        const int gc = col0 + wn * 64 + n * 16 + l15;
        const float bv = bias[gc];
#pragma unroll
        for (int m = 0; m < 4; m++) {
            const int rbase = row0 + wm * 64 + m * 16 + kq * 4;
#pragma unroll
            for (int r = 0; r < 4; r++) {
                const int gr = rbase + r;
                if (gr < M) {
                    const float v = fmaxf(acc[m][n][r] + bv, 0.f);
                    C[(size_t)gr * 256 + gc] = f2b(v);
                }
            }
        }
    }
}

// ---------- head: o = A[M,256](bf16) @ W[256,16] + b; out = log_softmax(o) ----------
__global__ __launch_bounds__(256) void head_kernel(const ushort* __restrict__ A,
                                                    const float* __restrict__ W,
                                                    const float* __restrict__ bias,
                                                    float* __restrict__ out, int M) {
    __shared__ float Ws[4096];  // [256][16]
    for (int i = threadIdx.x; i < 1024; i += 256)
        *(float4*)&Ws[i * 4] = *(const float4*)&W[i * 4];
    __syncthreads();

    const int r = threadIdx.x >> 4, c = threadIdx.x & 15;
    const int gm = blockIdx.x * 16 + r;
    float acc = 0.f;
    if (gm < M) {
        const ushort* a = &A[(size_t)gm * 256];
#pragma unroll 4
        for (int k = 0; k < 256; k += 8) {
            const uint4 v = *(const uint4*)&a[k];  // 8 bf16
            acc += b2f((ushort)v.x)         * Ws[(k + 0) * 16 + c];
            acc += b2f((ushort)(v.x >> 16)) * Ws[(k + 1) * 16 + c];
            acc += b2f((ushort)v.y)         * Ws[(k + 2) * 16 + c];
            acc += b2f((ushort)(v.y >> 16)) * Ws[(k + 3) * 16 + c];
            acc += b2f((ushort)v.z)         * Ws[(k + 4) * 16 + c];
            acc += b2f((ushort)(v.z >> 16)) * Ws[(k + 5) * 16 + c];
            acc += b2f((ushort)v.w)         * Ws[(k + 6) * 16 + c];
            acc += b2f((ushort)(v.w >> 16)) * Ws[(k + 7) * 16 + c];
        }
        acc += bias[c];
    }
    float m = acc;
#pragma unroll
    for (int o = 8; o; o >>= 1) m = fmaxf(m, __shfl_xor(m, o, 16));
    const float e = expf(acc - m);
    float s = e;
#pragma unroll
    for (int o = 8; o; o >>= 1) s += __shfl_xor(s, o, 16);
    if (gm < M) out[(size_t)gm * 16 + c] = (acc - m) - logf(s);
}

extern "C" void kernel_launch(void* const* d_in, const int* in_sizes, int n_in,
                              void* d_out, int out_size, void* d_ws, size_t ws_size,
                              hipStream_t stream) {
    (void)in_sizes; (void)n_in; (void)out_size; (void)ws_size;
    const float* x   = (const float*)d_in[0];
    const void*  ei  = d_in[1];
    const float* w1a = (const float*)d_in[2];
    const float* b1a = (const float*)d_in[3];
    const float* w2a = (const float*)d_in[4];
    const float* b2a = (const float*)d_in[5];
    const float* w1b = (const float*)d_in[6];
    const float* b1b = (const float*)d_in[7];
    const float* w2b = (const float*)d_in[8];
    const float* b2b = (const float*)d_in[9];
    float* out = (float*)d_out;

    // ws layout (ushort region first, then ints)
    ushort* XB   = (ushort*)d_ws;                 // [NN][128] bf16
    ushort* BA   = XB + (size_t)NN * 128;         // [NN][256] bf16
    ushort* BB   = BA + (size_t)NN * 256;         // [NN][256] bf16
    ushort* Wt1a = BB + (size_t)NN * 256;         // [256][128]
    ushort* Wt2a = Wt1a + 256 * 128;              // [256][256]
    ushort* Wt1b = Wt2a + 256 * 256;              // [256][256]
    int* idx     = (int*)(Wt1b + 256 * 256);      // 2*NE
    int* flag    = idx + 2 * NE;
    int* deg     = flag + 1;                      // NN
    int* rowptr  = deg + NN;                      // NN+1
    int* cursor  = rowptr + NN + 1;               // NN
    int* csr_src = cursor + NN;                   // NE

    // ---- edge index normalize + CSR ----
    detect_idx_kernel<<<1, 256, 0, stream>>>((const int*)ei, flag);
    convert_idx_kernel<<<(2 * NE + 255) / 256, 256, 0, stream>>>(ei, flag, idx, 2 * NE);
    const int* srcI = idx;
    const int* dstI = idx + NE;
    hipMemsetAsync(deg, 0, NN * sizeof(int), stream);
    count_deg_kernel<<<(NE + 255) / 256, 256, 0, stream>>>(dstI, deg);
    scan_kernel<<<1, 1024, 0, stream>>>(deg, rowptr, cursor);
    fill_csr_kernel<<<(NE + 255) / 256, 256, 0, stream>>>(srcI, dstI, cursor, csr_src);

    // ---- bf16 conversions ----
    cvt_f32_bf16_kernel<<<(NN * 128 / 4 + 255) / 256, 256, 0, stream>>>(x, XB, NN * 128 / 4);
    transpose_cvt_kernel<<<(128 * 256 + 255) / 256, 256, 0, stream>>>(w1a, Wt1a, 128, 256);
    transpose_cvt_kernel<<<(256 * 256 + 255) / 256, 256, 0, stream>>>(w2a, Wt2a, 256, 256);
    transpose_cvt_kernel<<<(256 * 256 + 255) / 256, 256, 0, stream>>>(w1b, Wt1b, 256, 256);

    const int aggBlocks = (NN + 3) / 4;
    const dim3 gg((NN + 127) / 128, 2);

    // ---- conv1 ----
    aggregate_bf16_kernel<128><<<aggBlocks, 256, 0, stream>>>(XB, BA, rowptr, csr_src);
    gemm_bf16_kernel<128><<<gg, 256, 0, stream>>>(BA, Wt1a, b1a, BB, NN);  // m1
    gemm_bf16_kernel<256><<<gg, 256, 0, stream>>>(BB, Wt2a, b2a, BA, NN);  // h1 (incl. outer relu)

    // ---- conv2 ----
    aggregate_bf16_kernel<256><<<aggBlocks, 256, 0, stream>>>(BA, BB, rowptr, csr_src);
    gemm_bf16_kernel<256><<<gg, 256, 0, stream>>>(BB, Wt1b, b1b, BA, NN);  // m2
    head_kernel<<<(NN + 15) / 16, 256, 0, stream>>>(BA, w2b, b2b, out, NN);
}

// Round 7
// 290.941 us; speedup vs baseline: 11.5855x; 1.3534x over previous
//
#include <hip/hip_runtime.h>

#define NN 50000
#define NE 600000
#define SCAN_BLOCKS 196  // 196*256 = 50176 >= NN

typedef short v8s __attribute__((ext_vector_type(8)));
typedef float v4f __attribute__((ext_vector_type(4)));

#define LDSW 40  // shorts per LDS tile row: 32 data + 8 pad (80B, 16B-aligned)

__device__ __forceinline__ float b2f(ushort u) {
    union { unsigned u; float f; } v; v.u = ((unsigned)u) << 16; return v.f;
}
__device__ __forceinline__ ushort f2b(float f) {
    union { float f; unsigned u; } v; v.f = f;
    unsigned r = v.u + 0x7FFFu + ((v.u >> 16) & 1u);  // RNE
    return (ushort)(r >> 16);
}

// ---------- edge-index dtype detection (int32 vs int64 storage) ----------
__global__ __launch_bounds__(256) void detect_idx_kernel(const int* __restrict__ raw,
                                                          int* __restrict__ flag) {
    __shared__ int cnt;
    if (threadIdx.x == 0) cnt = 0;
    __syncthreads();
    int c = 0;
    for (int i = threadIdx.x; i < 2048; i += 256)
        if (raw[2 * i + 1] != 0) c++;
    atomicAdd(&cnt, c);
    __syncthreads();
    if (threadIdx.x == 0) *flag = (cnt > 10) ? 1 : 0;  // 1 => int32 layout
}

// convert + fused degree count (dst half feeds deg atomics)
__global__ __launch_bounds__(256) void convert_idx_kernel(const void* __restrict__ raw,
                                                           const int* __restrict__ flag,
                                                           int* __restrict__ out,
                                                           int* __restrict__ deg, int n) {
    int i = blockIdx.x * 256 + threadIdx.x;
    if (i >= n) return;
    int v;
    if (*flag) v = ((const int*)raw)[i];
    else       v = (int)((const long long*)raw)[i];
    out[i] = v;
    if (i >= NE) atomicAdd(&deg[v], 1);  // dst half
}

// ---------- hierarchical scan: deg[NN] -> rowptr[NN+1], cursor[NN] ----------
__global__ __launch_bounds__(256) void block_sum_kernel(const int* __restrict__ deg,
                                                         int* __restrict__ bsum) {
    const int i = blockIdx.x * 256 + threadIdx.x;
    int v = (i < NN) ? deg[i] : 0;
#pragma unroll
    for (int o = 32; o; o >>= 1) v += __shfl_down(v, o, 64);
    __shared__ int ws[4];
    if ((threadIdx.x & 63) == 0) ws[threadIdx.x >> 6] = v;
    __syncthreads();
    if (threadIdx.x == 0) bsum[blockIdx.x] = ws[0] + ws[1] + ws[2] + ws[3];
}

__global__ __launch_bounds__(256) void scan_sums_kernel(const int* __restrict__ bsum,
                                                         int* __restrict__ boff,
                                                         int* __restrict__ rowptr) {
    __shared__ int tmp[256];
    const int t = threadIdx.x;
    const int v = (t < SCAN_BLOCKS) ? bsum[t] : 0;
    tmp[t] = v;
    __syncthreads();
#pragma unroll
    for (int off = 1; off < 256; off <<= 1) {
        int u = (t >= off) ? tmp[t - off] : 0;
        __syncthreads();
        tmp[t] += u;
        __syncthreads();
    }
    boff[t] = tmp[t] - v;  // exclusive
    if (t == 255) rowptr[NN] = tmp[255];
}

__global__ __launch_bounds__(256) void block_scan_kernel(const int* __restrict__ deg,
                                                          const int* __restrict__ boff,
                                                          int* __restrict__ rowptr,
                                                          int* __restrict__ cursor) {
    const int t = threadIdx.x;
    const int i = blockIdx.x * 256 + t;
    const int lane = t & 63, w = t >> 6;
    const int v = (i < NN) ? deg[i] : 0;
    int s = v;
#pragma unroll
    for (int o = 1; o < 64; o <<= 1) {
        int u = __shfl_up(s, o, 64);
        if (lane >= o) s += u;
    }
    __shared__ int wsum[4];
    if (lane == 63) wsum[w] = s;
    __syncthreads();
    int wpre = 0;
    for (int k = 0; k < w; k++) wpre += wsum[k];
    const int excl = boff[blockIdx.x] + wpre + s - v;
    if (i < NN) {
        rowptr[i] = excl;
        cursor[i] = excl;
    }
}

__global__ __launch_bounds__(256) void fill_csr_kernel(const int* __restrict__ srcIdx,
                                                        const int* __restrict__ dstIdx,
                                                        int* __restrict__ cursor,
                                                        int* __restrict__ csr_src) {
    int e = blockIdx.x * 256 + threadIdx.x;
    if (e >= NE) return;
    int pos = atomicAdd(&cursor[dstIdx[e]], 1);
    csr_src[pos] = srcIdx[e];
}

// ---------- fp32 -> bf16 converters ----------
__global__ __launch_bounds__(256) void cvt_f32_bf16_kernel(const float* __restrict__ in,
                                                            ushort* __restrict__ out, int n4) {
    int i = blockIdx.x * 256 + threadIdx.x;
    if (i >= n4) return;
    const float4 v = *(const float4*)&in[(size_t)i * 4];
    ushort4 o;
    o.x = f2b(v.x); o.y = f2b(v.y); o.z = f2b(v.z); o.w = f2b(v.w);
    *(ushort4*)&out[(size_t)i * 4] = o;
}

// out[n*K+k] = bf16(in[k*N+n])  (weights: tiny, once per call)
__global__ __launch_bounds__(256) void transpose_cvt_kernel(const float* __restrict__ in,
                                                             ushort* __restrict__ out,
                                                             int K, int N) {
    int idx = blockIdx.x * 256 + threadIdx.x;
    if (idx >= K * N) return;
    int n = idx / K, k = idx - n * K;
    out[idx] = f2b(in[(size_t)k * N + n]);
}

// ---------- gather-aggregate (bf16 in/out, fp32 accum) ----------
template <int D>
__global__ __launch_bounds__(256) void aggregate_bf16_kernel(const ushort* __restrict__ feat,
                                                              ushort* __restrict__ z,
                                                              const int* __restrict__ rowptr,
                                                              const int* __restrict__ csr_src) {
    const int node = blockIdx.x * 4 + (threadIdx.x >> 6);
    const int lane = threadIdx.x & 63;
    if (node >= NN) return;
    const int rbeg = rowptr[node];
    const int rend = rowptr[node + 1];

    if (D == 256) {
        const size_t base = (size_t)node * 256 + lane * 4;
        uint2 sv = *(const uint2*)&feat[base];
        float a0 = b2f((ushort)sv.x), a1 = b2f((ushort)(sv.x >> 16));
        float a2 = b2f((ushort)sv.y), a3 = b2f((ushort)(sv.y >> 16));
        int j = rbeg;
        for (; j + 3 < rend; j += 4) {
            const int s0 = csr_src[j], s1 = csr_src[j + 1];
            const int s2 = csr_src[j + 2], s3 = csr_src[j + 3];
            const uint2 v0 = *(const uint2*)&feat[(size_t)s0 * 256 + lane * 4];
            const uint2 v1 = *(const uint2*)&feat[(size_t)s1 * 256 + lane * 4];
            const uint2 v2 = *(const uint2*)&feat[(size_t)s2 * 256 + lane * 4];
            const uint2 v3 = *(const uint2*)&feat[(size_t)s3 * 256 + lane * 4];
            a0 += b2f((ushort)v0.x) + b2f((ushort)v1.x) + b2f((ushort)v2.x) + b2f((ushort)v3.x);
            a1 += b2f((ushort)(v0.x >> 16)) + b2f((ushort)(v1.x >> 16)) + b2f((ushort)(v2.x >> 16)) + b2f((ushort)(v3.x >> 16));
            a2 += b2f((ushort)v0.y) + b2f((ushort)v1.y) + b2f((ushort)v2.y) + b2f((ushort)v3.y);
            a3 += b2f((ushort)(v0.y >> 16)) + b2f((ushort)(v1.y >> 16)) + b2f((ushort)(v2.y >> 16)) + b2f((ushort)(v3.y >> 16));
        }
        for (; j < rend; j++) {
            const uint2 v = *(const uint2*)&feat[(size_t)csr_src[j] * 256 + lane * 4];
            a0 += b2f((ushort)v.x); a1 += b2f((ushort)(v.x >> 16));
            a2 += b2f((ushort)v.y); a3 += b2f((ushort)(v.y >> 16));
        }
        uint2 o;
        o.x = (uint)f2b(a0) | ((uint)f2b(a1) << 16);
        o.y = (uint)f2b(a2) | ((uint)f2b(a3) << 16);
        *(uint2*)&z[base] = o;
    } else {  // D == 128
        const size_t base = (size_t)node * 128 + lane * 2;
        uint sv = *(const uint*)&feat[base];
        float a0 = b2f((ushort)sv), a1 = b2f((ushort)(sv >> 16));
        int j = rbeg;
        for (; j + 3 < rend; j += 4) {
            const int s0 = csr_src[j], s1 = csr_src[j + 1];
            const int s2 = csr_src[j + 2], s3 = csr_src[j + 3];
            const uint v0 = *(const uint*)&feat[(size_t)s0 * 128 + lane * 2];
            const uint v1 = *(const uint*)&feat[(size_t)s1 * 128 + lane * 2];
            const uint v2 = *(const uint*)&feat[(size_t)s2 * 128 + lane * 2];
            const uint v3 = *(const uint*)&feat[(size_t)s3 * 128 + lane * 2];
            a0 += b2f((ushort)v0) + b2f((ushort)v1) + b2f((ushort)v2) + b2f((ushort)v3);
            a1 += b2f((ushort)(v0 >> 16)) + b2f((ushort)(v1 >> 16)) + b2f((ushort)(v2 >> 16)) + b2f((ushort)(v3 >> 16));
        }
        for (; j < rend; j++) {
            const uint v = *(const uint*)&feat[(size_t)csr_src[j] * 128 + lane * 2];
            a0 += b2f((ushort)v); a1 += b2f((ushort)(v >> 16));
        }
        *(uint*)&z[base] = (uint)f2b(a0) | ((uint)f2b(a1) << 16);
    }
}

// ---------- bf16 MFMA GEMM: C[M,256] = relu(A[M,K] @ W + bias), W given as Wt[256][K] ----------
template <int K>
__global__ __launch_bounds__(256) void gemm_bf16_kernel(const ushort* __restrict__ A,
                                                         const ushort* __restrict__ Bt,
                                                         const float* __restrict__ bias,
                                                         ushort* __restrict__ C,
                                                         int M) {
    __shared__ ushort lA[128 * LDSW];
    __shared__ ushort lB[128 * LDSW];
    const int tid = threadIdx.x;
    const int lane = tid & 63;
    const int wv = tid >> 6;
    const int wm = wv >> 1, wn = wv & 1;
    const int row0 = blockIdx.x * 128;
    const int col0 = blockIdx.y * 128;
    const int l15 = lane & 15;
    const int kq = lane >> 4;   // 0..3
    const int sr = tid >> 1;
    const int sc = (tid & 1) * 16;

    v4f acc[4][4];
#pragma unroll
    for (int m = 0; m < 4; m++)
#pragma unroll
        for (int n = 0; n < 4; n++) acc[m][n] = (v4f){0.f, 0.f, 0.f, 0.f};

    for (int k0 = 0; k0 < K; k0 += 32) {
        const int gr = row0 + sr;
        v8s a0 = {}, a1 = {};
        if (gr < M) {
            a0 = *(const v8s*)&A[(size_t)gr * K + k0 + sc];
            a1 = *(const v8s*)&A[(size_t)gr * K + k0 + sc + 8];
        }
        const v8s b0 = *(const v8s*)&Bt[(size_t)(col0 + sr) * K + k0 + sc];
        const v8s b1 = *(const v8s*)&Bt[(size_t)(col0 + sr) * K + k0 + sc + 8];
        *(v8s*)&lA[sr * LDSW + sc]     = a0;
        *(v8s*)&lA[sr * LDSW + sc + 8] = a1;
        *(v8s*)&lB[sr * LDSW + sc]     = b0;
        *(v8s*)&lB[sr * LDSW + sc + 8] = b1;
        __syncthreads();

        v8s af[4], bf[4];
#pragma unroll
        for (int m = 0; m < 4; m++)
            af[m] = *(const v8s*)&lA[(wm * 64 + m * 16 + l15) * LDSW + kq * 8];
#pragma unroll
        for (int n = 0; n < 4; n++)
            bf[n] = *(const v8s*)&lB[(wn * 64 + n * 16 + l15) * LDSW + kq * 8];
#pragma unroll
        for (int m = 0; m < 4; m++)
#pragma unroll
            for (int n = 0; n < 4; n++)
                acc[m][n] = __builtin_amdgcn_mfma_f32_16x16x32_bf16(af[m], bf[n], acc[m][n], 0, 0, 0);
        __syncthreads();
    }

#pragma unroll
    for (int n = 0; n < 4; n++) {
        const int gc = col0 + wn * 64 + n * 16 + l15;
        const float bv = bias[gc];
#pragma unroll
        for (int m = 0; m < 4; m++) {
            const int rbase = row0 + wm * 64 + m * 16 + kq * 4;
#pragma unroll
            for (int r = 0; r < 4; r++) {
                const int gr = rbase + r;
                if (gr < M) {
                    const float v = fmaxf(acc[m][n][r] + bv, 0.f);
                    C[(size_t)gr * 256 + gc] = f2b(v);
                }
            }
        }
    }
}

// ---------- head: o = A[M,256](bf16) @ W[256,16] + b; out = log_softmax(o) ----------
__global__ __launch_bounds__(256) void head_kernel(const ushort* __restrict__ A,
                                                    const float* __restrict__ W,
                                                    const float* __restrict__ bias,
                                                    float* __restrict__ out, int M) {
    __shared__ float Ws[4096];  // [256][16]
    for (int i = threadIdx.x; i < 1024; i += 256)
        *(float4*)&Ws[i * 4] = *(const float4*)&W[i * 4];
    __syncthreads();

    const int r = threadIdx.x >> 4, c = threadIdx.x & 15;
    const int gm = blockIdx.x * 16 + r;
    float acc = 0.f;
    if (gm < M) {
        const ushort* a = &A[(size_t)gm * 256];
#pragma unroll 4
        for (int k = 0; k < 256; k += 8) {
            const uint4 v = *(const uint4*)&a[k];  // 8 bf16
            acc += b2f((ushort)v.x)         * Ws[(k + 0) * 16 + c];
            acc += b2f((ushort)(v.x >> 16)) * Ws[(k + 1) * 16 + c];
            acc += b2f((ushort)v.y)         * Ws[(k + 2) * 16 + c];
            acc += b2f((ushort)(v.y >> 16)) * Ws[(k + 3) * 16 + c];
            acc += b2f((ushort)v.z)         * Ws[(k + 4) * 16 + c];
            acc += b2f((ushort)(v.z >> 16)) * Ws[(k + 5) * 16 + c];
            acc += b2f((ushort)v.w)         * Ws[(k + 6) * 16 + c];
            acc += b2f((ushort)(v.w >> 16)) * Ws[(k + 7) * 16 + c];
        }
        acc += bias[c];
    }
    float m = acc;
#pragma unroll
    for (int o = 8; o; o >>= 1) m = fmaxf(m, __shfl_xor(m, o, 16));
    const float e = expf(acc - m);
    float s = e;
#pragma unroll
    for (int o = 8; o; o >>= 1) s += __shfl_xor(s, o, 16);
    if (gm < M) out[(size_t)gm * 16 + c] = (acc - m) - logf(s);
}

extern "C" void kernel_launch(void* const* d_in, const int* in_sizes, int n_in,
                              void* d_out, int out_size, void* d_ws, size_t ws_size,
                              hipStream_t stream) {
    (void)in_sizes; (void)n_in; (void)out_size; (void)ws_size;
    const float* x   = (const float*)d_in[0];
    const void*  ei  = d_in[1];
    const float* w1a = (const float*)d_in[2];
    const float* b1a = (const float*)d_in[3];
    const float* w2a = (const float*)d_in[4];
    const float* b2a = (const float*)d_in[5];
    const float* w1b = (const float*)d_in[6];
    const float* b1b = (const float*)d_in[7];
    const float* w2b = (const float*)d_in[8];
    const float* b2b = (const float*)d_in[9];
    float* out = (float*)d_out;

    // ws layout (ushort region first, then ints)
    ushort* XB   = (ushort*)d_ws;                 // [NN][128] bf16
    ushort* BA   = XB + (size_t)NN * 128;         // [NN][256] bf16
    ushort* BB   = BA + (size_t)NN * 256;         // [NN][256] bf16
    ushort* Wt1a = BB + (size_t)NN * 256;         // [256][128]
    ushort* Wt2a = Wt1a + 256 * 128;              // [256][256]
    ushort* Wt1b = Wt2a + 256 * 256;              // [256][256]
    int* idx     = (int*)(Wt1b + 256 * 256);      // 2*NE
    int* flag    = idx + 2 * NE;
    int* deg     = flag + 1;                      // NN
    int* rowptr  = deg + NN;                      // NN+1
    int* cursor  = rowptr + NN + 1;               // NN
    int* csr_src = cursor + NN;                   // NE
    int* bsum    = csr_src + NE;                  // SCAN_BLOCKS
    int* boff    = bsum + SCAN_BLOCKS;            // 256

    // ---- edge index normalize + CSR ----
    detect_idx_kernel<<<1, 256, 0, stream>>>((const int*)ei, flag);
    hipMemsetAsync(deg, 0, NN * sizeof(int), stream);
    convert_idx_kernel<<<(2 * NE + 255) / 256, 256, 0, stream>>>(ei, flag, idx, deg, 2 * NE);
    const int* srcI = idx;
    const int* dstI = idx + NE;
    block_sum_kernel<<<SCAN_BLOCKS, 256, 0, stream>>>(deg, bsum);
    scan_sums_kernel<<<1, 256, 0, stream>>>(bsum, boff, rowptr);
    block_scan_kernel<<<SCAN_BLOCKS, 256, 0, stream>>>(deg, boff, rowptr, cursor);
    fill_csr_kernel<<<(NE + 255) / 256, 256, 0, stream>>>(srcI, dstI, cursor, csr_src);

    // ---- bf16 conversions ----
    cvt_f32_bf16_kernel<<<(NN * 128 / 4 + 255) / 256, 256, 0, stream>>>(x, XB, NN * 128 / 4);
    transpose_cvt_kernel<<<(128 * 256 + 255) / 256, 256, 0, stream>>>(w1a, Wt1a, 128, 256);
    transpose_cvt_kernel<<<(256 * 256 + 255) / 256, 256, 0, stream>>>(w2a, Wt2a, 256, 256);
    transpose_cvt_kernel<<<(256 * 256 + 255) / 256, 256, 0, stream>>>(w1b, Wt1b, 256, 256);

    const int aggBlocks = (NN + 3) / 4;
    const dim3 gg((NN + 127) / 128, 2);

    // ---- conv1 ----
    aggregate_bf16_kernel<128><<<aggBlocks, 256, 0, stream>>>(XB, BA, rowptr, csr_src);
    gemm_bf16_kernel<128><<<gg, 256, 0, stream>>>(BA, Wt1a, b1a, BB, NN);  // m1
    gemm_bf16_kernel<256><<<gg, 256, 0, stream>>>(BB, Wt2a, b2a, BA, NN);  // h1 (incl. outer relu)

    // ---- conv2 ----
    aggregate_bf16_kernel<256><<<aggBlocks, 256, 0, stream>>>(BA, BB, rowptr, csr_src);
    gemm_bf16_kernel<256><<<gg, 256, 0, stream>>>(BB, Wt1b, b1b, BA, NN);  // m2
    head_kernel<<<(NN + 15) / 16, 256, 0, stream>>>(BA, w2b, b2b, out, NN);
}

// Round 8
// 248.324 us; speedup vs baseline: 13.5738x; 1.1716x over previous
//
#include <hip/hip_runtime.h>

#define NN 50000
#define NE 600000
#define SCAN_BLOCKS 196  // 196*256 = 50176 >= NN

typedef short v8s __attribute__((ext_vector_type(8)));
typedef float v4f __attribute__((ext_vector_type(4)));

#define LDSW 40   // shorts per K-tile row: 32 data + 8 pad
#define MTW  264  // shorts per m-tile row: 256 data + 8 pad

__device__ __forceinline__ float b2f(ushort u) {
    union { unsigned u; float f; } v; v.u = ((unsigned)u) << 16; return v.f;
}
__device__ __forceinline__ ushort f2b(float f) {
    union { float f; unsigned u; } v; v.f = f;
    unsigned r = v.u + 0x7FFFu + ((v.u >> 16) & 1u);  // RNE
    return (ushort)(r >> 16);
}

// ---------- edge-index dtype detection (int32 vs int64 storage) ----------
__global__ __launch_bounds__(256) void detect_idx_kernel(const int* __restrict__ raw,
                                                          int* __restrict__ flag) {
    __shared__ int cnt;
    if (threadIdx.x == 0) cnt = 0;
    __syncthreads();
    int c = 0;
    for (int i = threadIdx.x; i < 2048; i += 256)
        if (raw[2 * i + 1] != 0) c++;
    atomicAdd(&cnt, c);
    __syncthreads();
    if (threadIdx.x == 0) *flag = (cnt > 10) ? 1 : 0;  // 1 => int32 layout
}

// convert + fused degree count (dst half feeds deg atomics)
__global__ __launch_bounds__(256) void convert_idx_kernel(const void* __restrict__ raw,
                                                           const int* __restrict__ flag,
                                                           int* __restrict__ out,
                                                           int* __restrict__ deg, int n) {
    int i = blockIdx.x * 256 + threadIdx.x;
    if (i >= n) return;
    int v;
    if (*flag) v = ((const int*)raw)[i];
    else       v = (int)((const long long*)raw)[i];
    out[i] = v;
    if (i >= NE) atomicAdd(&deg[v], 1);  // dst half
}

// ---------- hierarchical scan: deg[NN] -> rowptr[NN+1], cursor[NN] ----------
__global__ __launch_bounds__(256) void block_sum_kernel(const int* __restrict__ deg,
                                                         int* __restrict__ bsum) {
    const int i = blockIdx.x * 256 + threadIdx.x;
    int v = (i < NN) ? deg[i] : 0;
#pragma unroll
    for (int o = 32; o; o >>= 1) v += __shfl_down(v, o, 64);
    __shared__ int ws[4];
    if ((threadIdx.x & 63) == 0) ws[threadIdx.x >> 6] = v;
    __syncthreads();
    if (threadIdx.x == 0) bsum[blockIdx.x] = ws[0] + ws[1] + ws[2] + ws[3];
}

__global__ __launch_bounds__(256) void scan_sums_kernel(const int* __restrict__ bsum,
                                                         int* __restrict__ boff,
                                                         int* __restrict__ rowptr) {
    __shared__ int tmp[256];
    const int t = threadIdx.x;
    const int v = (t < SCAN_BLOCKS) ? bsum[t] : 0;
    tmp[t] = v;
    __syncthreads();
#pragma unroll
    for (int off = 1; off < 256; off <<= 1) {
        int u = (t >= off) ? tmp[t - off] : 0;
        __syncthreads();
        tmp[t] += u;
        __syncthreads();
    }
    boff[t] = tmp[t] - v;  // exclusive
    if (t == 255) rowptr[NN] = tmp[255];
}

__global__ __launch_bounds__(256) void block_scan_kernel(const int* __restrict__ deg,
                                                          const int* __restrict__ boff,
                                                          int* __restrict__ rowptr,
                                                          int* __restrict__ cursor) {
    const int t = threadIdx.x;
    const int i = blockIdx.x * 256 + t;
    const int lane = t & 63, w = t >> 6;
    const int v = (i < NN) ? deg[i] : 0;
    int s = v;
#pragma unroll
    for (int o = 1; o < 64; o <<= 1) {
        int u = __shfl_up(s, o, 64);
        if (lane >= o) s += u;
    }
    __shared__ int wsum[4];
    if (lane == 63) wsum[w] = s;
    __syncthreads();
    int wpre = 0;
    for (int k = 0; k < w; k++) wpre += wsum[k];
    const int excl = boff[blockIdx.x] + wpre + s - v;
    if (i < NN) {
        rowptr[i] = excl;
        cursor[i] = excl;
    }
}

__global__ __launch_bounds__(256) void fill_csr_kernel(const int* __restrict__ srcIdx,
                                                        const int* __restrict__ dstIdx,
                                                        int* __restrict__ cursor,
                                                        int* __restrict__ csr_src) {
    int e = blockIdx.x * 256 + threadIdx.x;
    if (e >= NE) return;
    int pos = atomicAdd(&cursor[dstIdx[e]], 1);
    csr_src[pos] = srcIdx[e];
}

// ---------- fp32 -> bf16 converters ----------
__global__ __launch_bounds__(256) void cvt_f32_bf16_kernel(const float* __restrict__ in,
                                                            ushort* __restrict__ out, int n4) {
    int i = blockIdx.x * 256 + threadIdx.x;
    if (i >= n4) return;
    const float4 v = *(const float4*)&in[(size_t)i * 4];
    ushort4 o;
    o.x = f2b(v.x); o.y = f2b(v.y); o.z = f2b(v.z); o.w = f2b(v.w);
    *(ushort4*)&out[(size_t)i * 4] = o;
}

// out[n*K+k] = bf16(in[k*N+n])  (weights: tiny, once per call)
__global__ __launch_bounds__(256) void transpose_cvt_kernel(const float* __restrict__ in,
                                                             ushort* __restrict__ out,
                                                             int K, int N) {
    int idx = blockIdx.x * 256 + threadIdx.x;
    if (idx >= K * N) return;
    int n = idx / K, k = idx - n * K;
    out[idx] = f2b(in[(size_t)k * N + n]);
}

// ---------- gather-aggregate (bf16 in/out, fp32 accum) ----------
template <int D>
__global__ __launch_bounds__(256) void aggregate_bf16_kernel(const ushort* __restrict__ feat,
                                                              ushort* __restrict__ z,
                                                              const int* __restrict__ rowptr,
                                                              const int* __restrict__ csr_src) {
    const int node = blockIdx.x * 4 + (threadIdx.x >> 6);
    const int lane = threadIdx.x & 63;
    if (node >= NN) return;
    const int rbeg = rowptr[node];
    const int rend = rowptr[node + 1];

    if (D == 256) {
        const size_t base = (size_t)node * 256 + lane * 4;
        uint2 sv = *(const uint2*)&feat[base];
        float a0 = b2f((ushort)sv.x), a1 = b2f((ushort)(sv.x >> 16));
        float a2 = b2f((ushort)sv.y), a3 = b2f((ushort)(sv.y >> 16));
        int j = rbeg;
        for (; j + 3 < rend; j += 4) {
            const int s0 = csr_src[j], s1 = csr_src[j + 1];
            const int s2 = csr_src[j + 2], s3 = csr_src[j + 3];
            const uint2 v0 = *(const uint2*)&feat[(size_t)s0 * 256 + lane * 4];
            const uint2 v1 = *(const uint2*)&feat[(size_t)s1 * 256 + lane * 4];
            const uint2 v2 = *(const uint2*)&feat[(size_t)s2 * 256 + lane * 4];
            const uint2 v3 = *(const uint2*)&feat[(size_t)s3 * 256 + lane * 4];
            a0 += b2f((ushort)v0.x) + b2f((ushort)v1.x) + b2f((ushort)v2.x) + b2f((ushort)v3.x);
            a1 += b2f((ushort)(v0.x >> 16)) + b2f((ushort)(v1.x >> 16)) + b2f((ushort)(v2.x >> 16)) + b2f((ushort)(v3.x >> 16));
            a2 += b2f((ushort)v0.y) + b2f((ushort)v1.y) + b2f((ushort)v2.y) + b2f((ushort)v3.y);
            a3 += b2f((ushort)(v0.y >> 16)) + b2f((ushort)(v1.y >> 16)) + b2f((ushort)(v2.y >> 16)) + b2f((ushort)(v3.y >> 16));
        }
        for (; j < rend; j++) {
            const uint2 v = *(const uint2*)&feat[(size_t)csr_src[j] * 256 + lane * 4];
            a0 += b2f((ushort)v.x); a1 += b2f((ushort)(v.x >> 16));
            a2 += b2f((ushort)v.y); a3 += b2f((ushort)(v.y >> 16));
        }
        uint2 o;
        o.x = (uint)f2b(a0) | ((uint)f2b(a1) << 16);
        o.y = (uint)f2b(a2) | ((uint)f2b(a3) << 16);
        *(uint2*)&z[base] = o;
    } else {  // D == 128
        const size_t base = (size_t)node * 128 + lane * 2;
        uint sv = *(const uint*)&feat[base];
        float a0 = b2f((ushort)sv), a1 = b2f((ushort)(sv >> 16));
        int j = rbeg;
        for (; j + 3 < rend; j += 4) {
            const int s0 = csr_src[j], s1 = csr_src[j + 1];
            const int s2 = csr_src[j + 2], s3 = csr_src[j + 3];
            const uint v0 = *(const uint*)&feat[(size_t)s0 * 128 + lane * 2];
            const uint v1 = *(const uint*)&feat[(size_t)s1 * 128 + lane * 2];
            const uint v2 = *(const uint*)&feat[(size_t)s2 * 128 + lane * 2];
            const uint v3 = *(const uint*)&feat[(size_t)s3 * 128 + lane * 2];
            a0 += b2f((ushort)v0) + b2f((ushort)v1) + b2f((ushort)v2) + b2f((ushort)v3);
            a1 += b2f((ushort)(v0 >> 16)) + b2f((ushort)(v1 >> 16)) + b2f((ushort)(v2 >> 16)) + b2f((ushort)(v3 >> 16));
        }
        for (; j < rend; j++) {
            const uint v = *(const uint*)&feat[(size_t)csr_src[j] * 128 + lane * 2];
            a0 += b2f((ushort)v); a1 += b2f((ushort)(v >> 16));
        }
        *(uint*)&z[base] = (uint)f2b(a0) | ((uint)f2b(a1) << 16);
    }
}

// ---------- fused 2-layer MLP (+ optional log_softmax head) ----------
// Block: 64 rows, 256 threads (4 waves). Stage1: m = relu(A@W1t^T + b1) -> mT in LDS (bf16).
// Stage2 (!HEAD): C = relu(m@W2t^T + b2) -> bf16 global, Nout=256, 4 waves x 64 cols.
// Stage2 (HEAD):  o = m@W2t^T + b2 (Nout=16), log_softmax -> fp32 global; 4 waves x 16 rows.
// Fragment layouts (m89/m91-verified): A row=l&15, k=(l>>4)*8+j; B col=l&15 same k;
// D col=l&15, row=(l>>4)*4+reg.
template <int K1, bool HEAD>
__global__ __launch_bounds__(256) void fused_mlp_kernel(const ushort* __restrict__ A,
                                                         const ushort* __restrict__ W1t,
                                                         const float* __restrict__ b1,
                                                         const ushort* __restrict__ W2t,
                                                         const float* __restrict__ b2,
                                                         void* __restrict__ outp, int M) {
    __shared__ ushort lA[64 * LDSW];    //  5.0 KB: A k-tile [64][32]
    __shared__ ushort lB[256 * LDSW];   // 20.0 KB: W k-tile [256][32]
    __shared__ ushort mT[64 * MTW];     // 33.0 KB: stage1 output [64][256] bf16
    const int tid = threadIdx.x;
    const int lane = tid & 63;
    const int wv = tid >> 6;            // wave 0..3
    const int row0 = blockIdx.x * 64;
    const int l15 = lane & 15;
    const int kq = lane >> 4;           // 0..3
    const int ar = tid >> 2, ak = (tid & 3) * 8;  // A staging: row 0..63, k-slot

    v4f acc[4][4];
#pragma unroll
    for (int m = 0; m < 4; m++)
#pragma unroll
        for (int n = 0; n < 4; n++) acc[m][n] = (v4f){0.f, 0.f, 0.f, 0.f};

    // ---- stage 1: m = relu(A @ W1 + b1), cols split 4 waves x 64 ----
    for (int k0 = 0; k0 < K1; k0 += 32) {
        v8s av = {};
        if (row0 + ar < M) av = *(const v8s*)&A[(size_t)(row0 + ar) * K1 + k0 + ak];
        const size_t wb = (size_t)tid * K1 + k0;
        const v8s w0 = *(const v8s*)&W1t[wb];
        const v8s w1 = *(const v8s*)&W1t[wb + 8];
        const v8s w2 = *(const v8s*)&W1t[wb + 16];
        const v8s w3 = *(const v8s*)&W1t[wb + 24];
        *(v8s*)&lA[ar * LDSW + ak] = av;
        *(v8s*)&lB[tid * LDSW + 0]  = w0;
        *(v8s*)&lB[tid * LDSW + 8]  = w1;
        *(v8s*)&lB[tid * LDSW + 16] = w2;
        *(v8s*)&lB[tid * LDSW + 24] = w3;
        __syncthreads();
        v8s af[4], bf[4];
#pragma unroll
        for (int m = 0; m < 4; m++)
            af[m] = *(const v8s*)&lA[(m * 16 + l15) * LDSW + kq * 8];
#pragma unroll
        for (int n = 0; n < 4; n++)
            bf[n] = *(const v8s*)&lB[(wv * 64 + n * 16 + l15) * LDSW + kq * 8];
#pragma unroll
        for (int m = 0; m < 4; m++)
#pragma unroll
            for (int n = 0; n < 4; n++)
                acc[m][n] = __builtin_amdgcn_mfma_f32_16x16x32_bf16(af[m], bf[n], acc[m][n], 0, 0, 0);
        __syncthreads();
    }
    // stage1 epilogue: bias + relu -> mT (bf16)
#pragma unroll
    for (int n = 0; n < 4; n++) {
        const int gc = wv * 64 + n * 16 + l15;
        const float bv = b1[gc];
#pragma unroll
        for (int m = 0; m < 4; m++) {
#pragma unroll
            for (int r = 0; r < 4; r++) {
                const int row = m * 16 + kq * 4 + r;
                mT[row * MTW + gc] = f2b(fmaxf(acc[m][n][r] + bv, 0.f));
            }
        }
    }
    __syncthreads();

    if constexpr (!HEAD) {
        // ---- stage 2: C = relu(m @ W2 + b2), Nout=256 ----
#pragma unroll
        for (int m = 0; m < 4; m++)
#pragma unroll
            for (int n = 0; n < 4; n++) acc[m][n] = (v4f){0.f, 0.f, 0.f, 0.f};
        for (int k0 = 0; k0 < 256; k0 += 32) {
            const size_t wb = (size_t)tid * 256 + k0;
            const v8s w0 = *(const v8s*)&W2t[wb];
            const v8s w1 = *(const v8s*)&W2t[wb + 8];
            const v8s w2 = *(const v8s*)&W2t[wb + 16];
            const v8s w3 = *(const v8s*)&W2t[wb + 24];
            __syncthreads();  // protect lB from prior iteration's reads
            *(v8s*)&lB[tid * LDSW + 0]  = w0;
            *(v8s*)&lB[tid * LDSW + 8]  = w1;
            *(v8s*)&lB[tid * LDSW + 16] = w2;
            *(v8s*)&lB[tid * LDSW + 24] = w3;
            __syncthreads();
            v8s af[4], bf[4];
#pragma unroll
            for (int m = 0; m < 4; m++)
                af[m] = *(const v8s*)&mT[(m * 16 + l15) * MTW + k0 + kq * 8];
#pragma unroll
            for (int n = 0; n < 4; n++)
                bf[n] = *(const v8s*)&lB[(wv * 64 + n * 16 + l15) * LDSW + kq * 8];
#pragma unroll
            for (int m = 0; m < 4; m++)
#pragma unroll
                for (int n = 0; n < 4; n++)
                    acc[m][n] = __builtin_amdgcn_mfma_f32_16x16x32_bf16(af[m], bf[n], acc[m][n], 0, 0, 0);
        }
        ushort* C = (ushort*)outp;
#pragma unroll
        for (int n = 0; n < 4; n++) {
            const int gc = wv * 64 + n * 16 + l15;
            const float bv = b2[gc];
#pragma unroll
            for (int m = 0; m < 4; m++) {
                const int rbase = row0 + m * 16 + kq * 4;
#pragma unroll
                for (int r = 0; r < 4; r++) {
                    const int gr = rbase + r;
                    if (gr < M) C[(size_t)gr * 256 + gc] = f2b(fmaxf(acc[m][n][r] + bv, 0.f));
                }
            }
        }
    } else {
        // ---- stage 2 head: o = m @ W2b + b2 (16 cols), log_softmax, fp32 out ----
        // wave wv owns rows wv*16 .. wv*16+15
        v4f a1 = (v4f){0.f, 0.f, 0.f, 0.f};
        for (int k0 = 0; k0 < 256; k0 += 32) {
            v8s wreg = {};
            if (tid < 64) wreg = *(const v8s*)&W2t[(size_t)(tid >> 2) * 256 + k0 + (tid & 3) * 8];
            __syncthreads();  // protect lB from prior iteration's reads
            if (tid < 64) *(v8s*)&lB[(tid >> 2) * LDSW + (tid & 3) * 8] = wreg;
            __syncthreads();
            const v8s af = *(const v8s*)&mT[(wv * 16 + l15) * MTW + k0 + kq * 8];
            const v8s bf = *(const v8s*)&lB[l15 * LDSW + kq * 8];
            a1 = __builtin_amdgcn_mfma_f32_16x16x32_bf16(af, bf, a1, 0, 0, 0);
        }
        float* O = (float*)outp;
        const float bv = b2[l15];
#pragma unroll
        for (int r = 0; r < 4; r++) {
            const float v = a1[r] + bv;
            float mx = v;
#pragma unroll
            for (int o = 8; o; o >>= 1) mx = fmaxf(mx, __shfl_xor(mx, o, 16));
            const float e = expf(v - mx);
            float s = e;
#pragma unroll
            for (int o = 8; o; o >>= 1) s += __shfl_xor(s, o, 16);
            const int grow = row0 + wv * 16 + kq * 4 + r;
            if (grow < M) O[(size_t)grow * 16 + l15] = (v - mx) - logf(s);
        }
    }
}

extern "C" void kernel_launch(void* const* d_in, const int* in_sizes, int n_in,
                              void* d_out, int out_size, void* d_ws, size_t ws_size,
                              hipStream_t stream) {
    (void)in_sizes; (void)n_in; (void)out_size; (void)ws_size;
    const float* x   = (const float*)d_in[0];
    const void*  ei  = d_in[1];
    const float* w1a = (const float*)d_in[2];
    const float* b1a = (const float*)d_in[3];
    const float* w2a = (const float*)d_in[4];
    const float* b2a = (const float*)d_in[5];
    const float* w1b = (const float*)d_in[6];
    const float* b1b = (const float*)d_in[7];
    const float* w2b = (const float*)d_in[8];
    const float* b2b = (const float*)d_in[9];
    float* out = (float*)d_out;

    // ws layout (ushort region first, then ints)
    ushort* XB   = (ushort*)d_ws;                 // [NN][128] bf16: x
    ushort* Z1   = XB + (size_t)NN * 128;         // [NN][128] bf16: z1
    ushort* H1   = Z1 + (size_t)NN * 128;         // [NN][256] bf16: h1
    ushort* Z2   = H1 + (size_t)NN * 256;         // [NN][256] bf16: z2
    ushort* Wt1a = Z2 + (size_t)NN * 256;         // [256][128]
    ushort* Wt2a = Wt1a + 256 * 128;              // [256][256]
    ushort* Wt1b = Wt2a + 256 * 256;              // [256][256]
    ushort* Wt2b = Wt1b + 256 * 256;              // [16][256]
    int* idx     = (int*)(Wt2b + 16 * 256);       // 2*NE
    int* flag    = idx + 2 * NE;
    int* deg     = flag + 1;                      // NN
    int* rowptr  = deg + NN;                      // NN+1
    int* cursor  = rowptr + NN + 1;               // NN
    int* csr_src = cursor + NN;                   // NE
    int* bsum    = csr_src + NE;                  // SCAN_BLOCKS
    int* boff    = bsum + SCAN_BLOCKS;            // 256

    // ---- edge index normalize + CSR ----
    detect_idx_kernel<<<1, 256, 0, stream>>>((const int*)ei, flag);
    hipMemsetAsync(deg, 0, NN * sizeof(int), stream);
    convert_idx_kernel<<<(2 * NE + 255) / 256, 256, 0, stream>>>(ei, flag, idx, deg, 2 * NE);
    const int* srcI = idx;
    const int* dstI = idx + NE;
    block_sum_kernel<<<SCAN_BLOCKS, 256, 0, stream>>>(deg, bsum);
    scan_sums_kernel<<<1, 256, 0, stream>>>(bsum, boff, rowptr);
    block_scan_kernel<<<SCAN_BLOCKS, 256, 0, stream>>>(deg, boff, rowptr, cursor);
    fill_csr_kernel<<<(NE + 255) / 256, 256, 0, stream>>>(srcI, dstI, cursor, csr_src);

    // ---- bf16 conversions ----
    cvt_f32_bf16_kernel<<<(NN * 128 / 4 + 255) / 256, 256, 0, stream>>>(x, XB, NN * 128 / 4);
    transpose_cvt_kernel<<<(128 * 256 + 255) / 256, 256, 0, stream>>>(w1a, Wt1a, 128, 256);
    transpose_cvt_kernel<<<(256 * 256 + 255) / 256, 256, 0, stream>>>(w2a, Wt2a, 256, 256);
    transpose_cvt_kernel<<<(256 * 256 + 255) / 256, 256, 0, stream>>>(w1b, Wt1b, 256, 256);
    transpose_cvt_kernel<<<(256 * 16 + 255) / 256, 256, 0, stream>>>(w2b, Wt2b, 256, 16);

    const int aggBlocks = (NN + 3) / 4;
    const int mlpBlocks = (NN + 63) / 64;

    // ---- conv1: aggregate + fused MLP (z1 -> h1) ----
    aggregate_bf16_kernel<128><<<aggBlocks, 256, 0, stream>>>(XB, Z1, rowptr, csr_src);
    fused_mlp_kernel<128, false><<<mlpBlocks, 256, 0, stream>>>(Z1, Wt1a, b1a, Wt2a, b2a, H1, NN);

    // ---- conv2: aggregate + fused MLP + head (z2 -> out) ----
    aggregate_bf16_kernel<256><<<aggBlocks, 256, 0, stream>>>(H1, Z2, rowptr, csr_src);
    fused_mlp_kernel<256, true><<<mlpBlocks, 256, 0, stream>>>(Z2, Wt1b, b1b, Wt2b, b2b, out, NN);
}

// Round 9
// 244.237 us; speedup vs baseline: 13.8010x; 1.0167x over previous
//
#include <hip/hip_runtime.h>

#define NN 50000
#define NE 600000
#define SCAN_BLOCKS 196  // 196*256 = 50176 >= NN

typedef short v8s __attribute__((ext_vector_type(8)));
typedef float v4f __attribute__((ext_vector_type(4)));

#define LAW 72    // lA row stride in shorts: 64 data + 8 pad (144B, 16B-aligned)
#define MTW 264   // mT row stride in shorts: 256 data + 8 pad (528B, 16B-aligned)

__device__ __forceinline__ float b2f(ushort u) {
    union { unsigned u; float f; } v; v.u = ((unsigned)u) << 16; return v.f;
}
__device__ __forceinline__ ushort f2b(float f) {
    union { float f; unsigned u; } v; v.f = f;
    unsigned r = v.u + 0x7FFFu + ((v.u >> 16) & 1u);  // RNE
    return (ushort)(r >> 16);
}

// ---------- edge-index dtype detection (int32 vs int64 storage) ----------
__global__ __launch_bounds__(256) void detect_idx_kernel(const int* __restrict__ raw,
                                                          int* __restrict__ flag) {
    __shared__ int cnt;
    if (threadIdx.x == 0) cnt = 0;
    __syncthreads();
    int c = 0;
    for (int i = threadIdx.x; i < 2048; i += 256)
        if (raw[2 * i + 1] != 0) c++;
    atomicAdd(&cnt, c);
    __syncthreads();
    if (threadIdx.x == 0) *flag = (cnt > 10) ? 1 : 0;  // 1 => int32 layout
}

// convert + fused degree count (dst half feeds deg atomics)
__global__ __launch_bounds__(256) void convert_idx_kernel(const void* __restrict__ raw,
                                                           const int* __restrict__ flag,
                                                           int* __restrict__ out,
                                                           int* __restrict__ deg, int n) {
    int i = blockIdx.x * 256 + threadIdx.x;
    if (i >= n) return;
    int v;
    if (*flag) v = ((const int*)raw)[i];
    else       v = (int)((const long long*)raw)[i];
    out[i] = v;
    if (i >= NE) atomicAdd(&deg[v], 1);  // dst half
}

// ---------- hierarchical scan: deg[NN] -> rowptr[NN+1], cursor[NN] ----------
__global__ __launch_bounds__(256) void block_sum_kernel(const int* __restrict__ deg,
                                                         int* __restrict__ bsum) {
    const int i = blockIdx.x * 256 + threadIdx.x;
    int v = (i < NN) ? deg[i] : 0;
#pragma unroll
    for (int o = 32; o; o >>= 1) v += __shfl_down(v, o, 64);
    __shared__ int ws[4];
    if ((threadIdx.x & 63) == 0) ws[threadIdx.x >> 6] = v;
    __syncthreads();
    if (threadIdx.x == 0) bsum[blockIdx.x] = ws[0] + ws[1] + ws[2] + ws[3];
}

__global__ __launch_bounds__(256) void scan_sums_kernel(const int* __restrict__ bsum,
                                                         int* __restrict__ boff,
                                                         int* __restrict__ rowptr) {
    __shared__ int tmp[256];
    const int t = threadIdx.x;
    const int v = (t < SCAN_BLOCKS) ? bsum[t] : 0;
    tmp[t] = v;
    __syncthreads();
#pragma unroll
    for (int off = 1; off < 256; off <<= 1) {
        int u = (t >= off) ? tmp[t - off] : 0;
        __syncthreads();
        tmp[t] += u;
        __syncthreads();
    }
    boff[t] = tmp[t] - v;  // exclusive
    if (t == 255) rowptr[NN] = tmp[255];
}

__global__ __launch_bounds__(256) void block_scan_kernel(const int* __restrict__ deg,
                                                          const int* __restrict__ boff,
                                                          int* __restrict__ rowptr,
                                                          int* __restrict__ cursor) {
    const int t = threadIdx.x;
    const int i = blockIdx.x * 256 + t;
    const int lane = t & 63, w = t >> 6;
    const int v = (i < NN) ? deg[i] : 0;
    int s = v;
#pragma unroll
    for (int o = 1; o < 64; o <<= 1) {
        int u = __shfl_up(s, o, 64);
        if (lane >= o) s += u;
    }
    __shared__ int wsum[4];
    if (lane == 63) wsum[w] = s;
    __syncthreads();
    int wpre = 0;
    for (int k = 0; k < w; k++) wpre += wsum[k];
    const int excl = boff[blockIdx.x] + wpre + s - v;
    if (i < NN) {
        rowptr[i] = excl;
        cursor[i] = excl;
    }
}

__global__ __launch_bounds__(256) void fill_csr_kernel(const int* __restrict__ srcIdx,
                                                        const int* __restrict__ dstIdx,
                                                        int* __restrict__ cursor,
                                                        int* __restrict__ csr_src) {
    int e = blockIdx.x * 256 + threadIdx.x;
    if (e >= NE) return;
    int pos = atomicAdd(&cursor[dstIdx[e]], 1);
    csr_src[pos] = srcIdx[e];
}

// ---------- fp32 -> bf16 converters ----------
__global__ __launch_bounds__(256) void cvt_f32_bf16_kernel(const float* __restrict__ in,
                                                            ushort* __restrict__ out, int n4) {
    int i = blockIdx.x * 256 + threadIdx.x;
    if (i >= n4) return;
    const float4 v = *(const float4*)&in[(size_t)i * 4];
    ushort4 o;
    o.x = f2b(v.x); o.y = f2b(v.y); o.z = f2b(v.z); o.w = f2b(v.w);
    *(ushort4*)&out[(size_t)i * 4] = o;
}

// out[n*K+k] = bf16(in[k*N+n])  (weights: tiny, once per call)
__global__ __launch_bounds__(256) void transpose_cvt_kernel(const float* __restrict__ in,
                                                             ushort* __restrict__ out,
                                                             int K, int N) {
    int idx = blockIdx.x * 256 + threadIdx.x;
    if (idx >= K * N) return;
    int n = idx / K, k = idx - n * K;
    out[idx] = f2b(in[(size_t)k * N + n]);
}

// ---------- gather-aggregate (bf16 in/out, fp32 accum) ----------
template <int D>
__global__ __launch_bounds__(256) void aggregate_bf16_kernel(const ushort* __restrict__ feat,
                                                              ushort* __restrict__ z,
                                                              const int* __restrict__ rowptr,
                                                              const int* __restrict__ csr_src) {
    const int node = blockIdx.x * 4 + (threadIdx.x >> 6);
    const int lane = threadIdx.x & 63;
    if (node >= NN) return;
    const int rbeg = rowptr[node];
    const int rend = rowptr[node + 1];

    if (D == 256) {
        const size_t base = (size_t)node * 256 + lane * 4;
        uint2 sv = *(const uint2*)&feat[base];
        float a0 = b2f((ushort)sv.x), a1 = b2f((ushort)(sv.x >> 16));
        float a2 = b2f((ushort)sv.y), a3 = b2f((ushort)(sv.y >> 16));
        int j = rbeg;
        for (; j + 3 < rend; j += 4) {
            const int s0 = csr_src[j], s1 = csr_src[j + 1];
            const int s2 = csr_src[j + 2], s3 = csr_src[j + 3];
            const uint2 v0 = *(const uint2*)&feat[(size_t)s0 * 256 + lane * 4];
            const uint2 v1 = *(const uint2*)&feat[(size_t)s1 * 256 + lane * 4];
            const uint2 v2 = *(const uint2*)&feat[(size_t)s2 * 256 + lane * 4];
            const uint2 v3 = *(const uint2*)&feat[(size_t)s3 * 256 + lane * 4];
            a0 += b2f((ushort)v0.x) + b2f((ushort)v1.x) + b2f((ushort)v2.x) + b2f((ushort)v3.x);
            a1 += b2f((ushort)(v0.x >> 16)) + b2f((ushort)(v1.x >> 16)) + b2f((ushort)(v2.x >> 16)) + b2f((ushort)(v3.x >> 16));
            a2 += b2f((ushort)v0.y) + b2f((ushort)v1.y) + b2f((ushort)v2.y) + b2f((ushort)v3.y);
            a3 += b2f((ushort)(v0.y >> 16)) + b2f((ushort)(v1.y >> 16)) + b2f((ushort)(v2.y >> 16)) + b2f((ushort)(v3.y >> 16));
        }
        for (; j < rend; j++) {
            const uint2 v = *(const uint2*)&feat[(size_t)csr_src[j] * 256 + lane * 4];
            a0 += b2f((ushort)v.x); a1 += b2f((ushort)(v.x >> 16));
            a2 += b2f((ushort)v.y); a3 += b2f((ushort)(v.y >> 16));
        }
        uint2 o;
        o.x = (uint)f2b(a0) | ((uint)f2b(a1) << 16);
        o.y = (uint)f2b(a2) | ((uint)f2b(a3) << 16);
        *(uint2*)&z[base] = o;
    } else {  // D == 128
        const size_t base = (size_t)node * 128 + lane * 2;
        uint sv = *(const uint*)&feat[base];
        float a0 = b2f((ushort)sv), a1 = b2f((ushort)(sv >> 16));
        int j = rbeg;
        for (; j + 3 < rend; j += 4) {
            const int s0 = csr_src[j], s1 = csr_src[j + 1];
            const int s2 = csr_src[j + 2], s3 = csr_src[j + 3];
            const uint v0 = *(const uint*)&feat[(size_t)s0 * 128 + lane * 2];
            const uint v1 = *(const uint*)&feat[(size_t)s1 * 128 + lane * 2];
            const uint v2 = *(const uint*)&feat[(size_t)s2 * 128 + lane * 2];
            const uint v3 = *(const uint*)&feat[(size_t)s3 * 128 + lane * 2];
            a0 += b2f((ushort)v0) + b2f((ushort)v1) + b2f((ushort)v2) + b2f((ushort)v3);
            a1 += b2f((ushort)(v0 >> 16)) + b2f((ushort)(v1 >> 16)) + b2f((ushort)(v2 >> 16)) + b2f((ushort)(v3 >> 16));
        }
        for (; j < rend; j++) {
            const uint v = *(const uint*)&feat[(size_t)csr_src[j] * 128 + lane * 2];
            a0 += b2f((ushort)v); a1 += b2f((ushort)(v >> 16));
        }
        *(uint*)&z[base] = (uint)f2b(a0) | ((uint)f2b(a1) << 16);
    }
}

// ---------- fused 2-layer MLP v2 (+ optional log_softmax head) ----------
// Block: 64 rows, 4 waves. W fragments live in REGISTERS (per-lane global loads:
// B-frag col=l&15 k-contiguous; one load = 16 full 64B lines, L2-resident).
// Stage 1: A k-tiles (BK=64) via double-buffered LDS -> 1 barrier/k-step; W1
// register-prefetched one step ahead. Stage 2: barrier-free (mT read-only,
// W2 in regs streamed in two half-K chunks).
// Fragment layouts (m89/m91-verified): A row=l&15, k=(l>>4)*8+j; B col=l&15
// same k; D col=l&15, row=(l>>4)*4+reg.
template <int K1, bool HEAD>
__global__ __launch_bounds__(256) void fused_mlp_kernel(const ushort* __restrict__ A,
                                                         const ushort* __restrict__ W1t,
                                                         const float* __restrict__ b1,
                                                         const ushort* __restrict__ W2t,
                                                         const float* __restrict__ b2,
                                                         void* __restrict__ outp, int M) {
    constexpr int S = K1 / 64;          // stage-1 k-steps
    __shared__ ushort lA[2][64 * LAW];  // 18.4 KB: dbuf A k-tile [64][64]
    __shared__ ushort mT[64 * MTW];     // 33.8 KB: stage-1 output [64][256] bf16
    const int tid = threadIdx.x;
    const int lane = tid & 63;
    const int wv = tid >> 6;            // wave 0..3
    const int row0 = blockIdx.x * 64;
    const int l15 = lane & 15;
    const int kq = lane >> 4;           // 0..3
    const int ar = tid >> 2, ak = (tid & 3) * 16;  // A staging: row, k-chunk

    const bool aok = (row0 + ar) < M;
    const ushort* Arow = A + (size_t)(row0 + ar) * K1 + ak;
    const ushort* w1base = W1t + (size_t)(wv * 64 + l15) * K1 + kq * 8;

    v4f acc[4][4];
#pragma unroll
    for (int m = 0; m < 4; m++)
#pragma unroll
        for (int n = 0; n < 4; n++) acc[m][n] = (v4f){0.f, 0.f, 0.f, 0.f};

    v8s a0 = {}, a1v = {};
    v8s w1cur[4][2], w1nxt[4][2];

    // ---- prologue: load step-0 A + W1, write lA[0] ----
    if (aok) { a0 = *(const v8s*)Arow; a1v = *(const v8s*)(Arow + 8); }
#pragma unroll
    for (int n = 0; n < 4; n++)
#pragma unroll
        for (int kk = 0; kk < 2; kk++)
            w1cur[n][kk] = *(const v8s*)(w1base + (size_t)n * 16 * K1 + kk * 32);
    *(v8s*)&lA[0][ar * LAW + ak]     = a0;
    *(v8s*)&lA[0][ar * LAW + ak + 8] = a1v;

    // ---- stage 1: m = relu(A @ W1 + b1) ----
#pragma unroll
    for (int s = 0; s < S; s++) {
        __syncthreads();  // lA[s&1] ready for all waves
        if (s + 1 < S) {  // prefetch next A + W1 (overlaps MFMA below)
            a0 = (v8s){}; a1v = (v8s){};
            if (aok) {
                a0  = *(const v8s*)(Arow + (s + 1) * 64);
                a1v = *(const v8s*)(Arow + (s + 1) * 64 + 8);
            }
#pragma unroll
            for (int n = 0; n < 4; n++)
#pragma unroll
                for (int kk = 0; kk < 2; kk++)
                    w1nxt[n][kk] = *(const v8s*)(w1base + (size_t)n * 16 * K1 + (s + 1) * 64 + kk * 32);
        }
        v8s af[4][2];
#pragma unroll
        for (int m = 0; m < 4; m++)
#pragma unroll
            for (int kk = 0; kk < 2; kk++)
                af[m][kk] = *(const v8s*)&lA[s & 1][(m * 16 + l15) * LAW + kk * 32 + kq * 8];
#pragma unroll
        for (int kk = 0; kk < 2; kk++)
#pragma unroll
            for (int m = 0; m < 4; m++)
#pragma unroll
                for (int n = 0; n < 4; n++)
                    acc[m][n] = __builtin_amdgcn_mfma_f32_16x16x32_bf16(af[m][kk], w1cur[n][kk], acc[m][n], 0, 0, 0);
        if (s + 1 < S) {
            *(v8s*)&lA[(s + 1) & 1][ar * LAW + ak]     = a0;
            *(v8s*)&lA[(s + 1) & 1][ar * LAW + ak + 8] = a1v;
#pragma unroll
            for (int n = 0; n < 4; n++)
#pragma unroll
                for (int kk = 0; kk < 2; kk++)
                    w1cur[n][kk] = w1nxt[n][kk];
        }
    }

    // ---- stage-1 epilogue: bias + relu -> mT (bf16) ----
#pragma unroll
    for (int n = 0; n < 4; n++) {
        const int gc = wv * 64 + n * 16 + l15;
        const float bv = b1[gc];
#pragma unroll
        for (int m = 0; m < 4; m++)
#pragma unroll
            for (int r = 0; r < 4; r++)
                mT[(m * 16 + kq * 4 + r) * MTW + gc] = f2b(fmaxf(acc[m][n][r] + bv, 0.f));
    }
    __syncthreads();  // mT ready; last barrier in the kernel

    if constexpr (!HEAD) {
        // ---- stage 2: C = relu(m @ W2 + b2), barrier-free ----
#pragma unroll
        for (int m = 0; m < 4; m++)
#pragma unroll
            for (int n = 0; n < 4; n++) acc[m][n] = (v4f){0.f, 0.f, 0.f, 0.f};
        const ushort* w2base = W2t + (size_t)(wv * 64 + l15) * 256 + kq * 8;
#pragma unroll
        for (int kh = 0; kh < 2; kh++) {
            v8s w2r[4][4];
#pragma unroll
            for (int n = 0; n < 4; n++)
#pragma unroll
                for (int kk = 0; kk < 4; kk++)
                    w2r[n][kk] = *(const v8s*)(w2base + (size_t)n * 16 * 256 + kh * 128 + kk * 32);
#pragma unroll
            for (int kk = 0; kk < 4; kk++) {
                v8s a2[4];
#pragma unroll
                for (int m = 0; m < 4; m++)
                    a2[m] = *(const v8s*)&mT[(m * 16 + l15) * MTW + kh * 128 + kk * 32 + kq * 8];
#pragma unroll
                for (int m = 0; m < 4; m++)
#pragma unroll
                    for (int n = 0; n < 4; n++)
                        acc[m][n] = __builtin_amdgcn_mfma_f32_16x16x32_bf16(a2[m], w2r[n][kk], acc[m][n], 0, 0, 0);
            }
        }
        ushort* C = (ushort*)outp;
#pragma unroll
        for (int n = 0; n < 4; n++) {
            const int gc = wv * 64 + n * 16 + l15;
            const float bv = b2[gc];
#pragma unroll
            for (int m = 0; m < 4; m++) {
                const int rbase = row0 + m * 16 + kq * 4;
#pragma unroll
                for (int r = 0; r < 4; r++) {
                    const int gr = rbase + r;
                    if (gr < M) C[(size_t)gr * 256 + gc] = f2b(fmaxf(acc[m][n][r] + bv, 0.f));
                }
            }
        }
    } else {
        // ---- stage 2 head: o = m @ W2b + b2 (16 cols), log_softmax, fp32 out ----
        // wave wv owns rows wv*16..wv*16+15; W2b (16x256) fully in regs
        v4f h = (v4f){0.f, 0.f, 0.f, 0.f};
        const ushort* w2base = W2t + (size_t)l15 * 256 + kq * 8;
        v8s w2r[8];
#pragma unroll
        for (int k8 = 0; k8 < 8; k8++)
            w2r[k8] = *(const v8s*)(w2base + k8 * 32);
#pragma unroll
        for (int k8 = 0; k8 < 8; k8++) {
            const v8s a2 = *(const v8s*)&mT[(wv * 16 + l15) * MTW + k8 * 32 + kq * 8];
            h = __builtin_amdgcn_mfma_f32_16x16x32_bf16(a2, w2r[k8], h, 0, 0, 0);
        }
        float* O = (float*)outp;
        const float bv = b2[l15];
#pragma unroll
        for (int r = 0; r < 4; r++) {
            const float v = h[r] + bv;
            float mx = v;
#pragma unroll
            for (int o = 8; o; o >>= 1) mx = fmaxf(mx, __shfl_xor(mx, o, 16));
            const float e = expf(v - mx);
            float s = e;
#pragma unroll
            for (int o = 8; o; o >>= 1) s += __shfl_xor(s, o, 16);
            const int grow = row0 + wv * 16 + kq * 4 + r;
            if (grow < M) O[(size_t)grow * 16 + l15] = (v - mx) - logf(s);
        }
    }
}

extern "C" void kernel_launch(void* const* d_in, const int* in_sizes, int n_in,
                              void* d_out, int out_size, void* d_ws, size_t ws_size,
                              hipStream_t stream) {
    (void)in_sizes; (void)n_in; (void)out_size; (void)ws_size;
    const float* x   = (const float*)d_in[0];
    const void*  ei  = d_in[1];
    const float* w1a = (const float*)d_in[2];
    const float* b1a = (const float*)d_in[3];
    const float* w2a = (const float*)d_in[4];
    const float* b2a = (const float*)d_in[5];
    const float* w1b = (const float*)d_in[6];
    const float* b1b = (const float*)d_in[7];
    const float* w2b = (const float*)d_in[8];
    const float* b2b = (const float*)d_in[9];
    float* out = (float*)d_out;

    // ws layout (ushort region first, then ints)
    ushort* XB   = (ushort*)d_ws;                 // [NN][128] bf16: x
    ushort* Z1   = XB + (size_t)NN * 128;         // [NN][128] bf16: z1
    ushort* H1   = Z1 + (size_t)NN * 128;         // [NN][256] bf16: h1
    ushort* Z2   = H1 + (size_t)NN * 256;         // [NN][256] bf16: z2
    ushort* Wt1a = Z2 + (size_t)NN * 256;         // [256][128]
    ushort* Wt2a = Wt1a + 256 * 128;              // [256][256]
    ushort* Wt1b = Wt2a + 256 * 256;              // [256][256]
    ushort* Wt2b = Wt1b + 256 * 256;              // [16][256]
    int* idx     = (int*)(Wt2b + 16 * 256);       // 2*NE
    int* flag    = idx + 2 * NE;
    int* deg     = flag + 1;                      // NN
    int* rowptr  = deg + NN;                      // NN+1
    int* cursor  = rowptr + NN + 1;               // NN
    int* csr_src = cursor + NN;                   // NE
    int* bsum    = csr_src + NE;                  // SCAN_BLOCKS
    int* boff    = bsum + SCAN_BLOCKS;            // 256

    // ---- edge index normalize + CSR ----
    detect_idx_kernel<<<1, 256, 0, stream>>>((const int*)ei, flag);
    hipMemsetAsync(deg, 0, NN * sizeof(int), stream);
    convert_idx_kernel<<<(2 * NE + 255) / 256, 256, 0, stream>>>(ei, flag, idx, deg, 2 * NE);
    const int* srcI = idx;
    const int* dstI = idx + NE;
    block_sum_kernel<<<SCAN_BLOCKS, 256, 0, stream>>>(deg, bsum);
    scan_sums_kernel<<<1, 256, 0, stream>>>(bsum, boff, rowptr);
    block_scan_kernel<<<SCAN_BLOCKS, 256, 0, stream>>>(deg, boff, rowptr, cursor);
    fill_csr_kernel<<<(NE + 255) / 256, 256, 0, stream>>>(srcI, dstI, cursor, csr_src);

    // ---- bf16 conversions ----
    cvt_f32_bf16_kernel<<<(NN * 128 / 4 + 255) / 256, 256, 0, stream>>>(x, XB, NN * 128 / 4);
    transpose_cvt_kernel<<<(128 * 256 + 255) / 256, 256, 0, stream>>>(w1a, Wt1a, 128, 256);
    transpose_cvt_kernel<<<(256 * 256 + 255) / 256, 256, 0, stream>>>(w2a, Wt2a, 256, 256);
    transpose_cvt_kernel<<<(256 * 256 + 255) / 256, 256, 0, stream>>>(w1b, Wt1b, 256, 256);
    transpose_cvt_kernel<<<(256 * 16 + 255) / 256, 256, 0, stream>>>(w2b, Wt2b, 256, 16);

    const int aggBlocks = (NN + 3) / 4;
    const int mlpBlocks = (NN + 63) / 64;

    // ---- conv1: aggregate + fused MLP (z1 -> h1) ----
    aggregate_bf16_kernel<128><<<aggBlocks, 256, 0, stream>>>(XB, Z1, rowptr, csr_src);
    fused_mlp_kernel<128, false><<<mlpBlocks, 256, 0, stream>>>(Z1, Wt1a, b1a, Wt2a, b2a, H1, NN);

    // ---- conv2: aggregate + fused MLP + head (z2 -> out) ----
    aggregate_bf16_kernel<256><<<aggBlocks, 256, 0, stream>>>(H1, Z2, rowptr, csr_src);
    fused_mlp_kernel<256, true><<<mlpBlocks, 256, 0, stream>>>(Z2, Wt1b, b1b, Wt2b, b2b, out, NN);
}